// Round 3
// baseline (386.664 us; speedup 1.0000x reference)
//
#include <hip/hip_runtime.h>
#include <hip/hip_bf16.h>
#include <math.h>

// ---------------------------------------------------------------------------
// Transformer block. R11:
//  - gemm_db replaces ALL gemms: 128x128 tile, BK=64, DOUBLE-buffered
//    global_load_lds staging, T3-minimum schedule (issue stage kt+1 ->
//    ds_read+MFMA kt -> one __syncthreads per K-step; syncthreads itself
//    drains vmcnt+lgkm, so loads overlap compute).
//  - LDS chunk XOR-swizzle, both sides (rule 21): linear LDS dest,
//    global SOURCE pre-swizzled (csub ^ rsub), ds_read chunk ^ (row&7).
//    Kills the 16-banks-only pattern of the linear [128][64] layout
//    (R10 counters: 12.6M bank conflicts, MfmaUtil 15.5%).
//  - No split-K, no atomics (R10: +48MB write traffic, 16.8M L2 atomics).
//    fc2/proj write f32 + bias + residual directly (mode 2).
//  - LN / attention / cvt unchanged.
// ---------------------------------------------------------------------------

#define TOKENS 4096
#define CDIM   1024
#define HEADS  16
#define DHEAD  64
#define HID    4096

typedef __attribute__((ext_vector_type(4))) float  floatx4;
typedef __attribute__((ext_vector_type(8))) short  short8;  // 8 x bf16 frag

// async global -> LDS, 16 bytes per lane. LDS dst is the WAVE-UNIFORM base;
// HW writes lane i's 16B at (base + i*16). Global src is per-lane.
__device__ __forceinline__ void gl_lds16(const void* g, void* l)
{
    __builtin_amdgcn_global_load_lds(
        (const __attribute__((address_space(1))) unsigned int*)g,
        (__attribute__((address_space(3))) unsigned int*)l,
        16, 0, 0);
}

// ---------------- fused fp32 -> bf16 weight convert ----------------
__global__ __launch_bounds__(256) void cvt_all(
    const float* __restrict__ s0, const float* __restrict__ s1,
    const float* __restrict__ s2, const float* __restrict__ s3,
    __hip_bfloat16* __restrict__ dst)
{
    long i = (long)blockIdx.x * 256 + threadIdx.x;   // float4 index, 3M total
    const float* src;
    long base;
    if (i < 768l * 1024)       { src = s0; base = 0; }
    else if (i < 1792l * 1024) { src = s1; base = 768l * 1024; }
    else if (i < 2816l * 1024) { src = s2; base = 1792l * 1024; }
    else                       { src = s3; base = 2816l * 1024; }
    float4 v = ((const float4*)src)[i - base];
    __hip_bfloat16 t[4];
    t[0] = __float2bfloat16(v.x);
    t[1] = __float2bfloat16(v.y);
    t[2] = __float2bfloat16(v.z);
    t[3] = __float2bfloat16(v.w);
    *(uint2*)(dst + 4l * i) = *(uint2*)t;
}

// ---------------- LayerNorm: fp32 in -> bf16 out (vectorized) --------------
__global__ __launch_bounds__(256) void ln_f32_kernel(
    const float* __restrict__ x, const float* __restrict__ g,
    const float* __restrict__ b, __hip_bfloat16* __restrict__ y, int C)
{
    int row = blockIdx.x;
    const float4* xr = (const float4*)(x + (long)row * C);
    uint2* yr = (uint2*)(y + (long)row * C);
    const int C4 = C >> 2;

    float s = 0.f, ss = 0.f;
    for (int i = threadIdx.x; i < C4; i += 256) {
        float4 v = xr[i];
        s  += v.x + v.y + v.z + v.w;
        ss += v.x * v.x + v.y * v.y + v.z * v.z + v.w * v.w;
    }
    #pragma unroll
    for (int d = 32; d; d >>= 1) {
        s  += __shfl_down(s, d);
        ss += __shfl_down(ss, d);
    }
    __shared__ float buf[4][2];
    int wid = threadIdx.x >> 6, lane = threadIdx.x & 63;
    if (lane == 0) { buf[wid][0] = s; buf[wid][1] = ss; }
    __syncthreads();
    if (threadIdx.x == 0) {
        s = buf[0][0] + buf[1][0] + buf[2][0] + buf[3][0];
        ss = buf[0][1] + buf[1][1] + buf[2][1] + buf[3][1];
        buf[0][0] = s; buf[0][1] = ss;
    }
    __syncthreads();
    s = buf[0][0]; ss = buf[0][1];

    float invC = 1.f / (float)C;
    float mu = s * invC;
    float var = ss * invC - mu * mu;
    float inv = rsqrtf(var + 1e-5f);
    const float4* gg = (const float4*)g;
    const float4* bb = (const float4*)b;
    for (int i = threadIdx.x; i < C4; i += 256) {
        float4 v = xr[i], gv = gg[i], bv = bb[i];
        __hip_bfloat16 t[4];
        t[0] = __float2bfloat16((v.x - mu) * inv * gv.x + bv.x);
        t[1] = __float2bfloat16((v.y - mu) * inv * gv.y + bv.y);
        t[2] = __float2bfloat16((v.z - mu) * inv * gv.z + bv.z);
        t[3] = __float2bfloat16((v.w - mu) * inv * gv.w + bv.w);
        yr[i] = *(uint2*)t;
    }
}

// ---------------- LayerNorm: bf16 in -> bf16 out (vectorized, in place ok) --
__global__ __launch_bounds__(256) void ln_bf16_kernel(
    const __hip_bfloat16* __restrict__ x, const float* __restrict__ g,
    const float* __restrict__ b, __hip_bfloat16* __restrict__ y, int C)
{
    int row = blockIdx.x;
    const uint4* xr = (const uint4*)(x + (long)row * C);
    uint4* yr = (uint4*)(y + (long)row * C);
    const int C8 = C >> 3;

    float s = 0.f, ss = 0.f;
    for (int i = threadIdx.x; i < C8; i += 256) {
        uint4 raw = xr[i];
        const __hip_bfloat16* p = (const __hip_bfloat16*)&raw;
        #pragma unroll
        for (int j = 0; j < 8; ++j) {
            float v = __bfloat162float(p[j]);
            s += v; ss += v * v;
        }
    }
    #pragma unroll
    for (int d = 32; d; d >>= 1) {
        s  += __shfl_down(s, d);
        ss += __shfl_down(ss, d);
    }
    __shared__ float buf[4][2];
    int wid = threadIdx.x >> 6, lane = threadIdx.x & 63;
    if (lane == 0) { buf[wid][0] = s; buf[wid][1] = ss; }
    __syncthreads();
    if (threadIdx.x == 0) {
        s = buf[0][0] + buf[1][0] + buf[2][0] + buf[3][0];
        ss = buf[0][1] + buf[1][1] + buf[2][1] + buf[3][1];
        buf[0][0] = s; buf[0][1] = ss;
    }
    __syncthreads();
    s = buf[0][0]; ss = buf[0][1];

    float invC = 1.f / (float)C;
    float mu = s * invC;
    float var = ss * invC - mu * mu;
    float inv = rsqrtf(var + 1e-5f);
    const float4* gg = (const float4*)g;
    const float4* bb = (const float4*)b;
    for (int i = threadIdx.x; i < C8; i += 256) {
        uint4 raw = xr[i];
        const __hip_bfloat16* p = (const __hip_bfloat16*)&raw;
        float4 g0 = gg[2 * i], g1 = gg[2 * i + 1];
        float4 b0 = bb[2 * i], b1 = bb[2 * i + 1];
        __hip_bfloat16 t[8];
        t[0] = __float2bfloat16((__bfloat162float(p[0]) - mu) * inv * g0.x + b0.x);
        t[1] = __float2bfloat16((__bfloat162float(p[1]) - mu) * inv * g0.y + b0.y);
        t[2] = __float2bfloat16((__bfloat162float(p[2]) - mu) * inv * g0.z + b0.z);
        t[3] = __float2bfloat16((__bfloat162float(p[3]) - mu) * inv * g0.w + b0.w);
        t[4] = __float2bfloat16((__bfloat162float(p[4]) - mu) * inv * g1.x + b1.x);
        t[5] = __float2bfloat16((__bfloat162float(p[5]) - mu) * inv * g1.y + b1.y);
        t[6] = __float2bfloat16((__bfloat162float(p[6]) - mu) * inv * g1.z + b1.z);
        t[7] = __float2bfloat16((__bfloat162float(p[7]) - mu) * inv * g1.w + b1.w);
        yr[i] = *(uint4*)t;
    }
}

// ---------------- gemm_db: 128x128 tile, BK=64, dbuf gl_lds, swizzled ------
// C = A[M,K] @ W[N,K]^T. 256 thr = 4 waves 2x2, wave tile 64x64.
// LDS: logical tile [128][64] bf16 in 16 segments of 1024 B (8 rows each);
// physical chunk p = logical chunk c XOR (row&7).  Staged by gl_lds with
// pre-swizzled global source; read with the same XOR -> all 32 banks hit.
// Schedule per K-step: STAGE(next) ; ds_read+MFMA(cur) ; __syncthreads().
// mode 0: bf16 out (+bias if non-null). mode 1: bf16 out, bias+gelu.
// mode 2: f32 out = acc + bias + residual.
__global__ __launch_bounds__(256, 2) void gemm_db(
    const __hip_bfloat16* __restrict__ A,
    const __hip_bfloat16* __restrict__ W,
    const float* __restrict__ bias, const float* __restrict__ residual,
    void* __restrict__ Cout, int M, int N, int K, int mode)
{
    __shared__ __align__(16) char Asl[2][16384];
    __shared__ __align__(16) char Bsl[2][16384];

    int tid = threadIdx.x;
    int wave = tid >> 6, lane = tid & 63;

    int mt, nt;
    {
        int gx = gridDim.x, gy = gridDim.y;
        int lin = blockIdx.y * gx + blockIdx.x;
        int chunk = gy >> 3;                 // gy = 32 in all uses
        int xcd = lin & 7, q = lin >> 3;
        mt = xcd * chunk + (q % chunk);
        nt = q / chunk;
    }
    int bm = mt * 128, bn = nt * 128;
    int wm = wave & 1, wn = wave >> 1;
    int fm = lane & 15, quad = lane >> 4;
    const int r7 = fm & 7;

    const int nk = K / 64;

    // staging: wave handles segments seg = wave*4+j (8 rows each).
    // lane l -> row seg*8 + (l>>3); SOURCE chunk pre-swizzled: (l&7)^(l>>3).
    const int rsub = lane >> 3;              // 0..7
    const int csub = (lane & 7) ^ rsub;      // inverse-swizzled 16B chunk
    const __hip_bfloat16* gA[4];
    const __hip_bfloat16* gB[4];
    int dseg[4];
    #pragma unroll
    for (int j = 0; j < 4; ++j) {
        int seg = wave * 4 + j;
        gA[j] = A + (long)(bm + seg * 8 + rsub) * K + csub * 8;
        gB[j] = W + (long)(bn + seg * 8 + rsub) * K + csub * 8;
        dseg[j] = seg * 1024;
    }

#define STAGE(b, kt) { \
    const long ko = (long)(kt) * 64; \
    _Pragma("unroll") \
    for (int j = 0; j < 4; ++j) { \
        gl_lds16(gA[j] + ko, Asl[b] + dseg[j]); \
        gl_lds16(gB[j] + ko, Bsl[b] + dseg[j]); \
    } }

    floatx4 acc[4][4] = {};

    STAGE(0, 0);
    __syncthreads();   // vmcnt(0) drain inside

    int cur = 0;
    for (int kt = 0; kt < nk; ++kt) {
        if (kt + 1 < nk) STAGE(cur ^ 1, kt + 1);   // issue next tile loads

        const char* Ab = Asl[cur];
        const char* Bb = Bsl[cur];
        #pragma unroll
        for (int kh = 0; kh < 2; ++kh) {
            // logical chunk c = kh*4+quad, row R: byte = R*128 + ((c^(R&7))<<4)
            const int xsw = ((kh * 4 + quad) ^ r7) << 4;
            short8 bq[4];
            #pragma unroll
            for (int j = 0; j < 4; ++j)
                bq[j] = *(const short8*)(Bb + (wn * 64 + j * 16 + fm) * 128 + xsw);
            #pragma unroll
            for (int i = 0; i < 4; ++i) {
                short8 af = *(const short8*)(Ab + (wm * 64 + i * 16 + fm) * 128 + xsw);
                #pragma unroll
                for (int j = 0; j < 4; ++j)
                    acc[i][j] = __builtin_amdgcn_mfma_f32_16x16x32_bf16(
                        af, bq[j], acc[i][j], 0, 0, 0);
            }
        }
        __syncthreads();   // drains vmcnt (next tile arrived) + lgkm; barrier
        cur ^= 1;
    }
#undef STAGE

    int mbase = bm + wm * 64;
    int nbase = bn + wn * 64;
    if (mode == 2) {
        float* Cf = (float*)Cout;
        #pragma unroll
        for (int i = 0; i < 4; ++i) {
            #pragma unroll
            for (int j = 0; j < 4; ++j) {
                int ncol = nbase + j * 16 + fm;
                float bv = bias[ncol];
                #pragma unroll
                for (int r = 0; r < 4; ++r) {
                    int mrow = mbase + i * 16 + quad * 4 + r;
                    long idx = (long)mrow * N + ncol;
                    Cf[idx] = acc[i][j][r] + bv + residual[idx];
                }
            }
        }
    } else {
        __hip_bfloat16* Cb = (__hip_bfloat16*)Cout;
        #pragma unroll
        for (int i = 0; i < 4; ++i) {
            #pragma unroll
            for (int j = 0; j < 4; ++j) {
                int ncol = nbase + j * 16 + fm;
                #pragma unroll
                for (int r = 0; r < 4; ++r) {
                    int mrow = mbase + i * 16 + quad * 4 + r;
                    float v = acc[i][j][r];
                    if (bias) v += bias[ncol];
                    if (mode == 1) {
                        float z = v * (1.5957691216f + 0.0713548162f * v * v);
                        v = v / (1.f + __expf(-z));
                    }
                    Cb[(long)mrow * N + ncol] = __float2bfloat16(v);
                }
            }
        }
    }
}

// ---------------- MFMA flash attention, pipelined (R5, unchanged) ----------
__global__ __launch_bounds__(256) void attn_mfma(
    const __hip_bfloat16* __restrict__ qkv, __hip_bfloat16* __restrict__ o_out)
{
    __shared__ __align__(16) char Ks[2][64 * 144];
    __shared__ __align__(16) char Vt[2][64 * 144];
    __shared__ __align__(16) char Ps[4 * 16 * 144];

    const int C3 = 3 * CDIM;
    int lin = blockIdx.x;
    int xcd = lin & 7, q = lin >> 3;
    int bh = xcd * 8 + (q >> 4);
    int qt = q & 15;
    int b = bh >> 4, hh = bh & 15;
    int tid = threadIdx.x, wave = tid >> 6, lane = tid & 63;
    int l = lane & 15, quad = lane >> 4;

    const __hip_bfloat16* qrow =
        qkv + (long)(b * 1024 + qt * 64 + wave * 16 + l) * C3 + hh * DHEAD;
    short8 qf0 = *(const short8*)(qrow + quad * 8);
    short8 qf1 = *(const short8*)(qrow + 32 + quad * 8);

    char* Psw = Ps + wave * (16 * 144);

    int sc = tid & 7;
    int skl = tid >> 3;

    const __hip_bfloat16* Kbase = qkv + (long)(b * 1024) * C3 + CDIM + hh * DHEAD;
    const __hip_bfloat16* Vbase = qkv + (long)(b * 1024) * C3 + 2 * CDIM + hh * DHEAD;
    const int kpp = skl ^ (sc << 2);

    floatx4 facc[4] = {};
    float mrun = -1e30f, lrun = 0.f;

    uint4 kA0, kA1, vA0, vA1;
    uint4 kB0, kB1, vB0, vB1;

#define GKV(t, k0, k1, v0, v1) { \
    const __hip_bfloat16* Kg = Kbase + (long)((t) * 64) * C3; \
    const __hip_bfloat16* Vg = Vbase + (long)((t) * 64) * C3; \
    k0 = *(const uint4*)(Kg + (long)skl * C3 + sc * 8); \
    k1 = *(const uint4*)(Kg + (long)(skl + 32) * C3 + sc * 8); \
    v0 = *(const uint4*)(Vg + (long)(2 * skl) * C3 + sc * 8); \
    v1 = *(const uint4*)(Vg + (long)(2 * skl + 1) * C3 + sc * 8); }
#define WKV(bf, k0, k1, v0, v1) { \
    *(uint4*)(Ks[bf] + skl * 144 + sc * 16) = k0; \
    *(uint4*)(Ks[bf] + (skl + 32) * 144 + sc * 16) = k1; \
    const ushort* e0 = (const ushort*)&v0; \
    const ushort* e1 = (const ushort*)&v1; \
    _Pragma("unroll") \
    for (int j = 0; j < 8; ++j) { \
        unsigned dw = (unsigned)e0[j] | ((unsigned)e1[j] << 16); \
        *(unsigned*)(Vt[bf] + (sc * 8 + j) * 144 + kpp * 4) = dw; \
    } }

    auto compute = [&](int buf) {
        floatx4 st[4] = {};
        #pragma unroll
        for (int kb = 0; kb < 4; ++kb) {
            short8 k0 = *(const short8*)(Ks[buf] + (kb * 16 + l) * 144 + quad * 16);
            short8 k1 = *(const short8*)(Ks[buf] + (kb * 16 + l) * 144 + 64 + quad * 16);
            st[kb] = __builtin_amdgcn_mfma_f32_16x16x32_bf16(k0, qf0, st[kb], 0, 0, 0);
            st[kb] = __builtin_amdgcn_mfma_f32_16x16x32_bf16(k1, qf1, st[kb], 0, 0, 0);
        }
        float p[16];
        float tm = -1e30f;
        #pragma unroll
        for (int kb = 0; kb < 4; ++kb)
            #pragma unroll
            for (int r = 0; r < 4; ++r) {
                float s = st[kb][r] * 0.125f;
                p[kb * 4 + r] = s;
                tm = fmaxf(tm, s);
            }
        tm = fmaxf(tm, __shfl_xor(tm, 16));
        tm = fmaxf(tm, __shfl_xor(tm, 32));
        float mn = fmaxf(mrun, tm);
        float alpha = __expf(mrun - mn);
        float psum = 0.f;
        #pragma unroll
        for (int i = 0; i < 16; ++i) { p[i] = __expf(p[i] - mn); psum += p[i]; }
        psum += __shfl_xor(psum, 16);
        psum += __shfl_xor(psum, 32);
        lrun = lrun * alpha + psum;
        mrun = mn;

        #pragma unroll
        for (int kb = 0; kb < 4; ++kb) {
            __hip_bfloat16 t[4];
            #pragma unroll
            for (int r = 0; r < 4; ++r) t[r] = __float2bfloat16(p[kb * 4 + r]);
            *(uint2*)(Psw + l * 144 + kb * 32 + quad * 8) = *(const uint2*)t;
        }

        float a0 = __shfl(alpha, quad * 4 + 0);
        float a1 = __shfl(alpha, quad * 4 + 1);
        float a2 = __shfl(alpha, quad * 4 + 2);
        float a3 = __shfl(alpha, quad * 4 + 3);
        #pragma unroll
        for (int db = 0; db < 4; ++db) {
            facc[db][0] *= a0; facc[db][1] *= a1;
            facc[db][2] *= a2; facc[db][3] *= a3;
        }

        short8 pf0 = *(const short8*)(Psw + l * 144 + quad * 16);
        short8 pf1 = *(const short8*)(Psw + l * 144 + 64 + quad * 16);
        #pragma unroll
        for (int db = 0; db < 4; ++db) {
            int d = db * 16 + l;
            int o3 = (d >> 3) & 7;
            short8 v0 = *(const short8*)(Vt[buf] + d * 144 + ((quad ^ o3) << 4));
            short8 v1 = *(const short8*)(Vt[buf] + d * 144 + (((4 + quad) ^ o3) << 4));
            facc[db] = __builtin_amdgcn_mfma_f32_16x16x32_bf16(pf0, v0, facc[db], 0, 0, 0);
            facc[db] = __builtin_amdgcn_mfma_f32_16x16x32_bf16(pf1, v1, facc[db], 0, 0, 0);
        }
    };

    GKV(0, kA0, kA1, vA0, vA1);
    #pragma unroll 1
    for (int kt = 0; kt < 16; kt += 2) {
        WKV(0, kA0, kA1, vA0, vA1);
        __syncthreads();
        GKV(kt + 1, kB0, kB1, vB0, vB1);
        compute(0);
        WKV(1, kB0, kB1, vB0, vB1);
        __syncthreads();
        if (kt + 2 < 16) GKV(kt + 2, kA0, kA1, vA0, vA1);
        compute(1);
    }
#undef GKV
#undef WKV

    float il0 = 1.f / __shfl(lrun, quad * 4 + 0);
    float il1 = 1.f / __shfl(lrun, quad * 4 + 1);
    float il2 = 1.f / __shfl(lrun, quad * 4 + 2);
    float il3 = 1.f / __shfl(lrun, quad * 4 + 3);
    __hip_bfloat16* orow =
        o_out + (long)(b * 1024 + qt * 64 + wave * 16) * CDIM + hh * DHEAD;
    #pragma unroll
    for (int db = 0; db < 4; ++db) {
        int col = db * 16 + l;
        orow[(quad * 4 + 0) * CDIM + col] = __float2bfloat16(facc[db][0] * il0);
        orow[(quad * 4 + 1) * CDIM + col] = __float2bfloat16(facc[db][1] * il1);
        orow[(quad * 4 + 2) * CDIM + col] = __float2bfloat16(facc[db][2] * il2);
        orow[(quad * 4 + 3) * CDIM + col] = __float2bfloat16(facc[db][3] * il3);
    }
}

// ---------------------------------------------------------------------------
extern "C" void kernel_launch(void* const* d_in, const int* in_sizes, int n_in,
                              void* d_out, int out_size, void* d_ws, size_t ws_size,
                              hipStream_t stream)
{
    const float* x      = (const float*)d_in[0];
    const float* qkv_w  = (const float*)d_in[1];
    const float* proj_w = (const float*)d_in[2];
    const float* proj_b = (const float*)d_in[3];
    const float* fc1_w  = (const float*)d_in[4];
    const float* fc1_b  = (const float*)d_in[5];
    const float* fc2_w  = (const float*)d_in[6];
    const float* fc2_b  = (const float*)d_in[7];
    const float* ln1_g  = (const float*)d_in[8];
    const float* ln1_b  = (const float*)d_in[9];
    const float* ln2_g  = (const float*)d_in[10];
    const float* ln2_b  = (const float*)d_in[11];
    const float* lnh_g  = (const float*)d_in[12];
    const float* lnh_b  = (const float*)d_in[13];

    float* out = (float*)d_out;

    __hip_bfloat16* wsb     = (__hip_bfloat16*)d_ws;
    __hip_bfloat16* qkvw_bf = wsb;
    __hip_bfloat16* fc1w_bf = qkvw_bf + 3l * 1024 * 1024;
    __hip_bfloat16* fc2w_bf = fc1w_bf + 4l * 1024 * 1024;
    __hip_bfloat16* projw_bf= fc2w_bf + 4l * 1024 * 1024;
    __hip_bfloat16* h_bf    = projw_bf + 1l * 1024 * 1024;
    __hip_bfloat16* qkv_bf  = h_bf + 4l * 1024 * 1024;
    __hip_bfloat16* o_bf    = qkv_bf + 12l * 1024 * 1024;
    __hip_bfloat16* u_bf    = o_bf + 4l * 1024 * 1024;

    // 0. all weights fp32 -> bf16
    cvt_all<<<12288, 256, 0, stream>>>(qkv_w, fc1_w, fc2_w, proj_w, qkvw_bf);

    // 1. h = LN1(x)
    ln_f32_kernel<<<TOKENS, 256, 0, stream>>>(x, ln1_g, ln1_b, h_bf, CDIM);
    // 2. qkv = h @ qkv_w^T
    gemm_db<<<dim3(3072 / 128, TOKENS / 128), 256, 0, stream>>>(
        h_bf, qkvw_bf, nullptr, nullptr, qkv_bf, TOKENS, 3072, CDIM, 0);
    // 3. o = attention(qkv)
    attn_mfma<<<1024, 256, 0, stream>>>(qkv_bf, o_bf);
    // 4. out = x + o @ proj_w^T + proj_b
    gemm_db<<<dim3(CDIM / 128, TOKENS / 128), 256, 0, stream>>>(
        o_bf, projw_bf, proj_b, x, out, TOKENS, CDIM, CDIM, 2);
    // 5. h2 = LN2(out)
    ln_f32_kernel<<<TOKENS, 256, 0, stream>>>(out, ln2_g, ln2_b, h_bf, CDIM);
    // 6. u = gelu(h2 @ fc1_w^T + fc1_b)
    gemm_db<<<dim3(HID / 128, TOKENS / 128), 256, 0, stream>>>(
        h_bf, fc1w_bf, fc1_b, nullptr, u_bf, TOKENS, HID, CDIM, 1);
    // 7. u = LNh(u) in place
    ln_bf16_kernel<<<TOKENS, 256, 0, stream>>>(u_bf, lnh_g, lnh_b, u_bf, HID);
    // 8. out = out + u @ fc2_w^T + fc2_b
    gemm_db<<<dim3(CDIM / 128, TOKENS / 128), 256, 0, stream>>>(
        u_bf, fc2w_bf, fc2_b, out, out, TOKENS, CDIM, HID, 2);
}

// Round 4
// 373.484 us; speedup vs baseline: 1.0353x; 1.0353x over previous
//
#include <hip/hip_runtime.h>
#include <hip/hip_bf16.h>
#include <math.h>

// ---------------------------------------------------------------------------
// Transformer block. R12:
//  - gemm_db templated on BK. proj & fc2 (grid=256 = 1 block/CU, grid-capped)
//    run BK=128: per-K-step compute (64 MFMA/wave = ~1240 cy/SIMD) now
//    exceeds HBM load latency (~900 cy), so the double-buffered loads are
//    fully hidden even at 1 wave/SIMD. LDS 128 KB/block (fits 160; occupancy
//    is grid-capped anyway -- R11 counters: Occupancy 10.6%, MfmaUtil 18%,
//    bank conflicts 0, i.e. latency-bound not conflict-bound).
//  - qkv & fc1 keep BK=64 (64 KB LDS -> 2 blocks/CU, 2 waves/SIMD TLP).
//  - Both-sides XOR chunk swizzle generalized: mask = BK/8-1 (7 or 15).
//  - LN / attention / cvt unchanged.
// ---------------------------------------------------------------------------

#define TOKENS 4096
#define CDIM   1024
#define HEADS  16
#define DHEAD  64
#define HID    4096

typedef __attribute__((ext_vector_type(4))) float  floatx4;
typedef __attribute__((ext_vector_type(8))) short  short8;  // 8 x bf16 frag

// async global -> LDS, 16 bytes per lane. LDS dst is the WAVE-UNIFORM base;
// HW writes lane i's 16B at (base + i*16). Global src is per-lane.
__device__ __forceinline__ void gl_lds16(const void* g, void* l)
{
    __builtin_amdgcn_global_load_lds(
        (const __attribute__((address_space(1))) unsigned int*)g,
        (__attribute__((address_space(3))) unsigned int*)l,
        16, 0, 0);
}

// ---------------- fused fp32 -> bf16 weight convert ----------------
__global__ __launch_bounds__(256) void cvt_all(
    const float* __restrict__ s0, const float* __restrict__ s1,
    const float* __restrict__ s2, const float* __restrict__ s3,
    __hip_bfloat16* __restrict__ dst)
{
    long i = (long)blockIdx.x * 256 + threadIdx.x;   // float4 index, 3M total
    const float* src;
    long base;
    if (i < 768l * 1024)       { src = s0; base = 0; }
    else if (i < 1792l * 1024) { src = s1; base = 768l * 1024; }
    else if (i < 2816l * 1024) { src = s2; base = 1792l * 1024; }
    else                       { src = s3; base = 2816l * 1024; }
    float4 v = ((const float4*)src)[i - base];
    __hip_bfloat16 t[4];
    t[0] = __float2bfloat16(v.x);
    t[1] = __float2bfloat16(v.y);
    t[2] = __float2bfloat16(v.z);
    t[3] = __float2bfloat16(v.w);
    *(uint2*)(dst + 4l * i) = *(uint2*)t;
}

// ---------------- LayerNorm: fp32 in -> bf16 out (vectorized) --------------
__global__ __launch_bounds__(256) void ln_f32_kernel(
    const float* __restrict__ x, const float* __restrict__ g,
    const float* __restrict__ b, __hip_bfloat16* __restrict__ y, int C)
{
    int row = blockIdx.x;
    const float4* xr = (const float4*)(x + (long)row * C);
    uint2* yr = (uint2*)(y + (long)row * C);
    const int C4 = C >> 2;

    float s = 0.f, ss = 0.f;
    for (int i = threadIdx.x; i < C4; i += 256) {
        float4 v = xr[i];
        s  += v.x + v.y + v.z + v.w;
        ss += v.x * v.x + v.y * v.y + v.z * v.z + v.w * v.w;
    }
    #pragma unroll
    for (int d = 32; d; d >>= 1) {
        s  += __shfl_down(s, d);
        ss += __shfl_down(ss, d);
    }
    __shared__ float buf[4][2];
    int wid = threadIdx.x >> 6, lane = threadIdx.x & 63;
    if (lane == 0) { buf[wid][0] = s; buf[wid][1] = ss; }
    __syncthreads();
    if (threadIdx.x == 0) {
        s = buf[0][0] + buf[1][0] + buf[2][0] + buf[3][0];
        ss = buf[0][1] + buf[1][1] + buf[2][1] + buf[3][1];
        buf[0][0] = s; buf[0][1] = ss;
    }
    __syncthreads();
    s = buf[0][0]; ss = buf[0][1];

    float invC = 1.f / (float)C;
    float mu = s * invC;
    float var = ss * invC - mu * mu;
    float inv = rsqrtf(var + 1e-5f);
    const float4* gg = (const float4*)g;
    const float4* bb = (const float4*)b;
    for (int i = threadIdx.x; i < C4; i += 256) {
        float4 v = xr[i], gv = gg[i], bv = bb[i];
        __hip_bfloat16 t[4];
        t[0] = __float2bfloat16((v.x - mu) * inv * gv.x + bv.x);
        t[1] = __float2bfloat16((v.y - mu) * inv * gv.y + bv.y);
        t[2] = __float2bfloat16((v.z - mu) * inv * gv.z + bv.z);
        t[3] = __float2bfloat16((v.w - mu) * inv * gv.w + bv.w);
        yr[i] = *(uint2*)t;
    }
}

// ---------------- LayerNorm: bf16 in -> bf16 out (vectorized, in place ok) --
__global__ __launch_bounds__(256) void ln_bf16_kernel(
    const __hip_bfloat16* __restrict__ x, const float* __restrict__ g,
    const float* __restrict__ b, __hip_bfloat16* __restrict__ y, int C)
{
    int row = blockIdx.x;
    const uint4* xr = (const uint4*)(x + (long)row * C);
    uint4* yr = (uint4*)(y + (long)row * C);
    const int C8 = C >> 3;

    float s = 0.f, ss = 0.f;
    for (int i = threadIdx.x; i < C8; i += 256) {
        uint4 raw = xr[i];
        const __hip_bfloat16* p = (const __hip_bfloat16*)&raw;
        #pragma unroll
        for (int j = 0; j < 8; ++j) {
            float v = __bfloat162float(p[j]);
            s += v; ss += v * v;
        }
    }
    #pragma unroll
    for (int d = 32; d; d >>= 1) {
        s  += __shfl_down(s, d);
        ss += __shfl_down(ss, d);
    }
    __shared__ float buf[4][2];
    int wid = threadIdx.x >> 6, lane = threadIdx.x & 63;
    if (lane == 0) { buf[wid][0] = s; buf[wid][1] = ss; }
    __syncthreads();
    if (threadIdx.x == 0) {
        s = buf[0][0] + buf[1][0] + buf[2][0] + buf[3][0];
        ss = buf[0][1] + buf[1][1] + buf[2][1] + buf[3][1];
        buf[0][0] = s; buf[0][1] = ss;
    }
    __syncthreads();
    s = buf[0][0]; ss = buf[0][1];

    float invC = 1.f / (float)C;
    float mu = s * invC;
    float var = ss * invC - mu * mu;
    float inv = rsqrtf(var + 1e-5f);
    const float4* gg = (const float4*)g;
    const float4* bb = (const float4*)b;
    for (int i = threadIdx.x; i < C8; i += 256) {
        uint4 raw = xr[i];
        const __hip_bfloat16* p = (const __hip_bfloat16*)&raw;
        float4 g0 = gg[2 * i], g1 = gg[2 * i + 1];
        float4 b0 = bb[2 * i], b1 = bb[2 * i + 1];
        __hip_bfloat16 t[8];
        t[0] = __float2bfloat16((__bfloat162float(p[0]) - mu) * inv * g0.x + b0.x);
        t[1] = __float2bfloat16((__bfloat162float(p[1]) - mu) * inv * g0.y + b0.y);
        t[2] = __float2bfloat16((__bfloat162float(p[2]) - mu) * inv * g0.z + b0.z);
        t[3] = __float2bfloat16((__bfloat162float(p[3]) - mu) * inv * g0.w + b0.w);
        t[4] = __float2bfloat16((__bfloat162float(p[4]) - mu) * inv * g1.x + b1.x);
        t[5] = __float2bfloat16((__bfloat162float(p[5]) - mu) * inv * g1.y + b1.y);
        t[6] = __float2bfloat16((__bfloat162float(p[6]) - mu) * inv * g1.z + b1.z);
        t[7] = __float2bfloat16((__bfloat162float(p[7]) - mu) * inv * g1.w + b1.w);
        yr[i] = *(uint4*)t;
    }
}

// ---------------- gemm_db<BK>: 128x128 tile, dbuf gl_lds, swizzled ---------
// C = A[M,K] @ W[N,K]^T. 256 thr = 4 waves 2x2, wave tile 64x64.
// LDS tile [128][BK] bf16 in 1KB segments; physical 16B-chunk p = logical
// chunk c XOR (row & MASK), MASK = BK/8-1. Staged via gl_lds with
// pre-swizzled global source; read with the same XOR -> conflict-free.
// Schedule per K-step: STAGE(next) ; ds_read+MFMA(cur) ; __syncthreads().
// mode 0: bf16 out (+bias if non-null). mode 1: bf16 out, bias+gelu.
// mode 2: f32 out = acc + bias + residual.
template<int BK>
__global__ __launch_bounds__(256, BK == 64 ? 2 : 1) void gemm_db(
    const __hip_bfloat16* __restrict__ A,
    const __hip_bfloat16* __restrict__ W,
    const float* __restrict__ bias, const float* __restrict__ residual,
    void* __restrict__ Cout, int M, int N, int K, int mode)
{
    constexpr int ROWSEG = 512 / BK;     // rows per 1KB staging segment
    constexpr int CHK    = BK / 8;       // 16B chunks per row
    constexpr int MASK   = CHK - 1;
    constexpr int NSEGW  = BK / 16;      // segments per wave (per matrix)
    constexpr int RS     = 2 * BK;       // LDS row stride in bytes
    constexpr int KH     = BK / 32;      // K=32 groups per K-step

    __shared__ __align__(16) char Asl[2][BK * 256];   // 128 rows * BK * 2B
    __shared__ __align__(16) char Bsl[2][BK * 256];

    int tid = threadIdx.x;
    int wave = tid >> 6, lane = tid & 63;

    int mt, nt;
    {
        int gx = gridDim.x, gy = gridDim.y;
        int lin = blockIdx.y * gx + blockIdx.x;
        int chunk = gy >> 3;                 // gy = 32 in all uses
        int xcd = lin & 7, q = lin >> 3;
        mt = xcd * chunk + (q % chunk);
        nt = q / chunk;
    }
    int bm = mt * 128, bn = nt * 128;
    int wm = wave & 1, wn = wave >> 1;
    int fm = lane & 15, quad = lane >> 4;

    const int nk = K / BK;

    // staging: wave handles segments seg = wave*NSEGW + j (ROWSEG rows each).
    // lane l -> row seg*ROWSEG + (l/CHK); SOURCE chunk pre-swizzled.
    const int rsub  = lane / CHK;
    const int cphys = lane & MASK;
    const __hip_bfloat16* gA[NSEGW];
    const __hip_bfloat16* gB[NSEGW];
    int dseg[NSEGW];
    #pragma unroll
    for (int j = 0; j < NSEGW; ++j) {
        int seg = wave * NSEGW + j;
        int row = seg * ROWSEG + rsub;
        int csrc = cphys ^ (row & MASK);
        gA[j] = A + (long)(bm + row) * K + csrc * 8;
        gB[j] = W + (long)(bn + row) * K + csrc * 8;
        dseg[j] = seg * 1024;
    }

#define STAGE(b, kt) { \
    const long ko = (long)(kt) * BK; \
    _Pragma("unroll") \
    for (int j = 0; j < NSEGW; ++j) { \
        gl_lds16(gA[j] + ko, Asl[b] + dseg[j]); \
        gl_lds16(gB[j] + ko, Bsl[b] + dseg[j]); \
    } }

    floatx4 acc[4][4] = {};

    STAGE(0, 0);
    __syncthreads();   // vmcnt(0) drain inside

    int cur = 0;
    for (int kt = 0; kt < nk; ++kt) {
        if (kt + 1 < nk) STAGE(cur ^ 1, kt + 1);   // issue next tile loads

        const char* Ab = Asl[cur];
        const char* Bb = Bsl[cur];
        #pragma unroll
        for (int kh = 0; kh < KH; ++kh) {
            // logical chunk c = kh*4+quad at row R (R&MASK == fm&MASK):
            const int xsw = (((kh * 4 + quad) ^ (fm & MASK)) << 4);
            short8 bq[4];
            #pragma unroll
            for (int j = 0; j < 4; ++j)
                bq[j] = *(const short8*)(Bb + (wn * 64 + j * 16 + fm) * RS + xsw);
            #pragma unroll
            for (int i = 0; i < 4; ++i) {
                short8 af = *(const short8*)(Ab + (wm * 64 + i * 16 + fm) * RS + xsw);
                #pragma unroll
                for (int j = 0; j < 4; ++j)
                    acc[i][j] = __builtin_amdgcn_mfma_f32_16x16x32_bf16(
                        af, bq[j], acc[i][j], 0, 0, 0);
            }
        }
        __syncthreads();   // drains vmcnt (next tile arrived) + lgkm; barrier
        cur ^= 1;
    }
#undef STAGE

    int mbase = bm + wm * 64;
    int nbase = bn + wn * 64;
    if (mode == 2) {
        float* Cf = (float*)Cout;
        #pragma unroll
        for (int i = 0; i < 4; ++i) {
            #pragma unroll
            for (int j = 0; j < 4; ++j) {
                int ncol = nbase + j * 16 + fm;
                float bv = bias[ncol];
                #pragma unroll
                for (int r = 0; r < 4; ++r) {
                    int mrow = mbase + i * 16 + quad * 4 + r;
                    long idx = (long)mrow * N + ncol;
                    Cf[idx] = acc[i][j][r] + bv + residual[idx];
                }
            }
        }
    } else {
        __hip_bfloat16* Cb = (__hip_bfloat16*)Cout;
        #pragma unroll
        for (int i = 0; i < 4; ++i) {
            #pragma unroll
            for (int j = 0; j < 4; ++j) {
                int ncol = nbase + j * 16 + fm;
                #pragma unroll
                for (int r = 0; r < 4; ++r) {
                    int mrow = mbase + i * 16 + quad * 4 + r;
                    float v = acc[i][j][r];
                    if (bias) v += bias[ncol];
                    if (mode == 1) {
                        float z = v * (1.5957691216f + 0.0713548162f * v * v);
                        v = v / (1.f + __expf(-z));
                    }
                    Cb[(long)mrow * N + ncol] = __float2bfloat16(v);
                }
            }
        }
    }
}

// ---------------- MFMA flash attention, pipelined (R5, unchanged) ----------
__global__ __launch_bounds__(256) void attn_mfma(
    const __hip_bfloat16* __restrict__ qkv, __hip_bfloat16* __restrict__ o_out)
{
    __shared__ __align__(16) char Ks[2][64 * 144];
    __shared__ __align__(16) char Vt[2][64 * 144];
    __shared__ __align__(16) char Ps[4 * 16 * 144];

    const int C3 = 3 * CDIM;
    int lin = blockIdx.x;
    int xcd = lin & 7, q = lin >> 3;
    int bh = xcd * 8 + (q >> 4);
    int qt = q & 15;
    int b = bh >> 4, hh = bh & 15;
    int tid = threadIdx.x, wave = tid >> 6, lane = tid & 63;
    int l = lane & 15, quad = lane >> 4;

    const __hip_bfloat16* qrow =
        qkv + (long)(b * 1024 + qt * 64 + wave * 16 + l) * C3 + hh * DHEAD;
    short8 qf0 = *(const short8*)(qrow + quad * 8);
    short8 qf1 = *(const short8*)(qrow + 32 + quad * 8);

    char* Psw = Ps + wave * (16 * 144);

    int sc = tid & 7;
    int skl = tid >> 3;

    const __hip_bfloat16* Kbase = qkv + (long)(b * 1024) * C3 + CDIM + hh * DHEAD;
    const __hip_bfloat16* Vbase = qkv + (long)(b * 1024) * C3 + 2 * CDIM + hh * DHEAD;
    const int kpp = skl ^ (sc << 2);

    floatx4 facc[4] = {};
    float mrun = -1e30f, lrun = 0.f;

    uint4 kA0, kA1, vA0, vA1;
    uint4 kB0, kB1, vB0, vB1;

#define GKV(t, k0, k1, v0, v1) { \
    const __hip_bfloat16* Kg = Kbase + (long)((t) * 64) * C3; \
    const __hip_bfloat16* Vg = Vbase + (long)((t) * 64) * C3; \
    k0 = *(const uint4*)(Kg + (long)skl * C3 + sc * 8); \
    k1 = *(const uint4*)(Kg + (long)(skl + 32) * C3 + sc * 8); \
    v0 = *(const uint4*)(Vg + (long)(2 * skl) * C3 + sc * 8); \
    v1 = *(const uint4*)(Vg + (long)(2 * skl + 1) * C3 + sc * 8); }
#define WKV(bf, k0, k1, v0, v1) { \
    *(uint4*)(Ks[bf] + skl * 144 + sc * 16) = k0; \
    *(uint4*)(Ks[bf] + (skl + 32) * 144 + sc * 16) = k1; \
    const ushort* e0 = (const ushort*)&v0; \
    const ushort* e1 = (const ushort*)&v1; \
    _Pragma("unroll") \
    for (int j = 0; j < 8; ++j) { \
        unsigned dw = (unsigned)e0[j] | ((unsigned)e1[j] << 16); \
        *(unsigned*)(Vt[bf] + (sc * 8 + j) * 144 + kpp * 4) = dw; \
    } }

    auto compute = [&](int buf) {
        floatx4 st[4] = {};
        #pragma unroll
        for (int kb = 0; kb < 4; ++kb) {
            short8 k0 = *(const short8*)(Ks[buf] + (kb * 16 + l) * 144 + quad * 16);
            short8 k1 = *(const short8*)(Ks[buf] + (kb * 16 + l) * 144 + 64 + quad * 16);
            st[kb] = __builtin_amdgcn_mfma_f32_16x16x32_bf16(k0, qf0, st[kb], 0, 0, 0);
            st[kb] = __builtin_amdgcn_mfma_f32_16x16x32_bf16(k1, qf1, st[kb], 0, 0, 0);
        }
        float p[16];
        float tm = -1e30f;
        #pragma unroll
        for (int kb = 0; kb < 4; ++kb)
            #pragma unroll
            for (int r = 0; r < 4; ++r) {
                float s = st[kb][r] * 0.125f;
                p[kb * 4 + r] = s;
                tm = fmaxf(tm, s);
            }
        tm = fmaxf(tm, __shfl_xor(tm, 16));
        tm = fmaxf(tm, __shfl_xor(tm, 32));
        float mn = fmaxf(mrun, tm);
        float alpha = __expf(mrun - mn);
        float psum = 0.f;
        #pragma unroll
        for (int i = 0; i < 16; ++i) { p[i] = __expf(p[i] - mn); psum += p[i]; }
        psum += __shfl_xor(psum, 16);
        psum += __shfl_xor(psum, 32);
        lrun = lrun * alpha + psum;
        mrun = mn;

        #pragma unroll
        for (int kb = 0; kb < 4; ++kb) {
            __hip_bfloat16 t[4];
            #pragma unroll
            for (int r = 0; r < 4; ++r) t[r] = __float2bfloat16(p[kb * 4 + r]);
            *(uint2*)(Psw + l * 144 + kb * 32 + quad * 8) = *(const uint2*)t;
        }

        float a0 = __shfl(alpha, quad * 4 + 0);
        float a1 = __shfl(alpha, quad * 4 + 1);
        float a2 = __shfl(alpha, quad * 4 + 2);
        float a3 = __shfl(alpha, quad * 4 + 3);
        #pragma unroll
        for (int db = 0; db < 4; ++db) {
            facc[db][0] *= a0; facc[db][1] *= a1;
            facc[db][2] *= a2; facc[db][3] *= a3;
        }

        short8 pf0 = *(const short8*)(Psw + l * 144 + quad * 16);
        short8 pf1 = *(const short8*)(Psw + l * 144 + 64 + quad * 16);
        #pragma unroll
        for (int db = 0; db < 4; ++db) {
            int d = db * 16 + l;
            int o3 = (d >> 3) & 7;
            short8 v0 = *(const short8*)(Vt[buf] + d * 144 + ((quad ^ o3) << 4));
            short8 v1 = *(const short8*)(Vt[buf] + d * 144 + (((4 + quad) ^ o3) << 4));
            facc[db] = __builtin_amdgcn_mfma_f32_16x16x32_bf16(pf0, v0, facc[db], 0, 0, 0);
            facc[db] = __builtin_amdgcn_mfma_f32_16x16x32_bf16(pf1, v1, facc[db], 0, 0, 0);
        }
    };

    GKV(0, kA0, kA1, vA0, vA1);
    #pragma unroll 1
    for (int kt = 0; kt < 16; kt += 2) {
        WKV(0, kA0, kA1, vA0, vA1);
        __syncthreads();
        GKV(kt + 1, kB0, kB1, vB0, vB1);
        compute(0);
        WKV(1, kB0, kB1, vB0, vB1);
        __syncthreads();
        if (kt + 2 < 16) GKV(kt + 2, kA0, kA1, vA0, vA1);
        compute(1);
    }
#undef GKV
#undef WKV

    float il0 = 1.f / __shfl(lrun, quad * 4 + 0);
    float il1 = 1.f / __shfl(lrun, quad * 4 + 1);
    float il2 = 1.f / __shfl(lrun, quad * 4 + 2);
    float il3 = 1.f / __shfl(lrun, quad * 4 + 3);
    __hip_bfloat16* orow =
        o_out + (long)(b * 1024 + qt * 64 + wave * 16) * CDIM + hh * DHEAD;
    #pragma unroll
    for (int db = 0; db < 4; ++db) {
        int col = db * 16 + l;
        orow[(quad * 4 + 0) * CDIM + col] = __float2bfloat16(facc[db][0] * il0);
        orow[(quad * 4 + 1) * CDIM + col] = __float2bfloat16(facc[db][1] * il1);
        orow[(quad * 4 + 2) * CDIM + col] = __float2bfloat16(facc[db][2] * il2);
        orow[(quad * 4 + 3) * CDIM + col] = __float2bfloat16(facc[db][3] * il3);
    }
}

// ---------------------------------------------------------------------------
extern "C" void kernel_launch(void* const* d_in, const int* in_sizes, int n_in,
                              void* d_out, int out_size, void* d_ws, size_t ws_size,
                              hipStream_t stream)
{
    const float* x      = (const float*)d_in[0];
    const float* qkv_w  = (const float*)d_in[1];
    const float* proj_w = (const float*)d_in[2];
    const float* proj_b = (const float*)d_in[3];
    const float* fc1_w  = (const float*)d_in[4];
    const float* fc1_b  = (const float*)d_in[5];
    const float* fc2_w  = (const float*)d_in[6];
    const float* fc2_b  = (const float*)d_in[7];
    const float* ln1_g  = (const float*)d_in[8];
    const float* ln1_b  = (const float*)d_in[9];
    const float* ln2_g  = (const float*)d_in[10];
    const float* ln2_b  = (const float*)d_in[11];
    const float* lnh_g  = (const float*)d_in[12];
    const float* lnh_b  = (const float*)d_in[13];

    float* out = (float*)d_out;

    __hip_bfloat16* wsb     = (__hip_bfloat16*)d_ws;
    __hip_bfloat16* qkvw_bf = wsb;
    __hip_bfloat16* fc1w_bf = qkvw_bf + 3l * 1024 * 1024;
    __hip_bfloat16* fc2w_bf = fc1w_bf + 4l * 1024 * 1024;
    __hip_bfloat16* projw_bf= fc2w_bf + 4l * 1024 * 1024;
    __hip_bfloat16* h_bf    = projw_bf + 1l * 1024 * 1024;
    __hip_bfloat16* qkv_bf  = h_bf + 4l * 1024 * 1024;
    __hip_bfloat16* o_bf    = qkv_bf + 12l * 1024 * 1024;
    __hip_bfloat16* u_bf    = o_bf + 4l * 1024 * 1024;

    // 0. all weights fp32 -> bf16
    cvt_all<<<12288, 256, 0, stream>>>(qkv_w, fc1_w, fc2_w, proj_w, qkvw_bf);

    // 1. h = LN1(x)
    ln_f32_kernel<<<TOKENS, 256, 0, stream>>>(x, ln1_g, ln1_b, h_bf, CDIM);
    // 2. qkv = h @ qkv_w^T  (768 blocks, 2/CU -> BK=64)
    gemm_db<64><<<dim3(3072 / 128, TOKENS / 128), 256, 0, stream>>>(
        h_bf, qkvw_bf, nullptr, nullptr, qkv_bf, TOKENS, 3072, CDIM, 0);
    // 3. o = attention(qkv)
    attn_mfma<<<1024, 256, 0, stream>>>(qkv_bf, o_bf);
    // 4. out = x + o @ proj_w^T + proj_b  (256 blocks, grid-capped -> BK=128)
    gemm_db<128><<<dim3(CDIM / 128, TOKENS / 128), 256, 0, stream>>>(
        o_bf, projw_bf, proj_b, x, out, TOKENS, CDIM, CDIM, 2);
    // 5. h2 = LN2(out)
    ln_f32_kernel<<<TOKENS, 256, 0, stream>>>(out, ln2_g, ln2_b, h_bf, CDIM);
    // 6. u = gelu(h2 @ fc1_w^T + fc1_b)  (1024 blocks, 2/CU -> BK=64)
    gemm_db<64><<<dim3(HID / 128, TOKENS / 128), 256, 0, stream>>>(
        h_bf, fc1w_bf, fc1_b, nullptr, u_bf, TOKENS, HID, CDIM, 1);
    // 7. u = LNh(u) in place
    ln_bf16_kernel<<<TOKENS, 256, 0, stream>>>(u_bf, lnh_g, lnh_b, u_bf, HID);
    // 8. out = out + u @ fc2_w^T + fc2_b  (256 blocks, grid-capped -> BK=128)
    gemm_db<128><<<dim3(CDIM / 128, TOKENS / 128), 256, 0, stream>>>(
        u_bf, fc2w_bf, fc2_b, out, out, TOKENS, CDIM, HID, 2);
}

// Round 6
// 358.029 us; speedup vs baseline: 1.0800x; 1.0432x over previous
//
#include <hip/hip_runtime.h>
#include <hip/hip_bf16.h>
#include <math.h>

// ---------------------------------------------------------------------------
// Transformer block. R14 (= R13 resubmit; container failed, audit found no
// hang/fault mechanism -- vmcnt ledger, barrier uniformity, OOB all clean):
//  - gemm8p (qkv, fc1): 256x256 tile, BK=64, 512 thr = 8 waves (2Mx4N),
//    wave tile 128x64. Phased schedule with COUNTED vmcnt (T3+T4):
//    2 phases/K-tile; per phase: issue 4 gl_lds (next tile's half) ||
//    12 ds_read_b128 || 32 MFMA (setprio, T5); phase ends
//    s_waitcnt vmcnt(4) + raw s_barrier. Tail vmcnt(0) @ (nk-1, h=0).
//    LDS 128 KB [buf][A/B][kh][256 x 64 B], chunk swizzle
//    phys = quad ^ ((row>>1)&3), source pre-swizzled (rule 21).
//  - proj & fc2 on gemm_db<128> (R12, passing).
//  - LN / attention / cvt unchanged.
// ---------------------------------------------------------------------------

#define TOKENS 4096
#define CDIM   1024
#define HEADS  16
#define DHEAD  64
#define HID    4096

typedef __attribute__((ext_vector_type(4))) float  floatx4;
typedef __attribute__((ext_vector_type(8))) short  short8;  // 8 x bf16 frag

// async global -> LDS, 16 bytes per lane. LDS dst is the WAVE-UNIFORM base;
// HW writes lane i's 16B at (base + i*16). Global src is per-lane.
__device__ __forceinline__ void gl_lds16(const void* g, void* l)
{
    __builtin_amdgcn_global_load_lds(
        (const __attribute__((address_space(1))) unsigned int*)g,
        (__attribute__((address_space(3))) unsigned int*)l,
        16, 0, 0);
}

// ---------------- fused fp32 -> bf16 weight convert ----------------
__global__ __launch_bounds__(256) void cvt_all(
    const float* __restrict__ s0, const float* __restrict__ s1,
    const float* __restrict__ s2, const float* __restrict__ s3,
    __hip_bfloat16* __restrict__ dst)
{
    long i = (long)blockIdx.x * 256 + threadIdx.x;   // float4 index, 3M total
    const float* src;
    long base;
    if (i < 768l * 1024)       { src = s0; base = 0; }
    else if (i < 1792l * 1024) { src = s1; base = 768l * 1024; }
    else if (i < 2816l * 1024) { src = s2; base = 1792l * 1024; }
    else                       { src = s3; base = 2816l * 1024; }
    float4 v = ((const float4*)src)[i - base];
    __hip_bfloat16 t[4];
    t[0] = __float2bfloat16(v.x);
    t[1] = __float2bfloat16(v.y);
    t[2] = __float2bfloat16(v.z);
    t[3] = __float2bfloat16(v.w);
    *(uint2*)(dst + 4l * i) = *(uint2*)t;
}

// ---------------- LayerNorm: fp32 in -> bf16 out (vectorized) --------------
__global__ __launch_bounds__(256) void ln_f32_kernel(
    const float* __restrict__ x, const float* __restrict__ g,
    const float* __restrict__ b, __hip_bfloat16* __restrict__ y, int C)
{
    int row = blockIdx.x;
    const float4* xr = (const float4*)(x + (long)row * C);
    uint2* yr = (uint2*)(y + (long)row * C);
    const int C4 = C >> 2;

    float s = 0.f, ss = 0.f;
    for (int i = threadIdx.x; i < C4; i += 256) {
        float4 v = xr[i];
        s  += v.x + v.y + v.z + v.w;
        ss += v.x * v.x + v.y * v.y + v.z * v.z + v.w * v.w;
    }
    #pragma unroll
    for (int d = 32; d; d >>= 1) {
        s  += __shfl_down(s, d);
        ss += __shfl_down(ss, d);
    }
    __shared__ float buf[4][2];
    int wid = threadIdx.x >> 6, lane = threadIdx.x & 63;
    if (lane == 0) { buf[wid][0] = s; buf[wid][1] = ss; }
    __syncthreads();
    if (threadIdx.x == 0) {
        s = buf[0][0] + buf[1][0] + buf[2][0] + buf[3][0];
        ss = buf[0][1] + buf[1][1] + buf[2][1] + buf[3][1];
        buf[0][0] = s; buf[0][1] = ss;
    }
    __syncthreads();
    s = buf[0][0]; ss = buf[0][1];

    float invC = 1.f / (float)C;
    float mu = s * invC;
    float var = ss * invC - mu * mu;
    float inv = rsqrtf(var + 1e-5f);
    const float4* gg = (const float4*)g;
    const float4* bb = (const float4*)b;
    for (int i = threadIdx.x; i < C4; i += 256) {
        float4 v = xr[i], gv = gg[i], bv = bb[i];
        __hip_bfloat16 t[4];
        t[0] = __float2bfloat16((v.x - mu) * inv * gv.x + bv.x);
        t[1] = __float2bfloat16((v.y - mu) * inv * gv.y + bv.y);
        t[2] = __float2bfloat16((v.z - mu) * inv * gv.z + bv.z);
        t[3] = __float2bfloat16((v.w - mu) * inv * gv.w + bv.w);
        yr[i] = *(uint2*)t;
    }
}

// ---------------- LayerNorm: bf16 in -> bf16 out (vectorized, in place ok) --
__global__ __launch_bounds__(256) void ln_bf16_kernel(
    const __hip_bfloat16* __restrict__ x, const float* __restrict__ g,
    const float* __restrict__ b, __hip_bfloat16* __restrict__ y, int C)
{
    int row = blockIdx.x;
    const uint4* xr = (const uint4*)(x + (long)row * C);
    uint4* yr = (uint4*)(y + (long)row * C);
    const int C8 = C >> 3;

    float s = 0.f, ss = 0.f;
    for (int i = threadIdx.x; i < C8; i += 256) {
        uint4 raw = xr[i];
        const __hip_bfloat16* p = (const __hip_bfloat16*)&raw;
        #pragma unroll
        for (int j = 0; j < 8; ++j) {
            float v = __bfloat162float(p[j]);
            s += v; ss += v * v;
        }
    }
    #pragma unroll
    for (int d = 32; d; d >>= 1) {
        s  += __shfl_down(s, d);
        ss += __shfl_down(ss, d);
    }
    __shared__ float buf[4][2];
    int wid = threadIdx.x >> 6, lane = threadIdx.x & 63;
    if (lane == 0) { buf[wid][0] = s; buf[wid][1] = ss; }
    __syncthreads();
    if (threadIdx.x == 0) {
        s = buf[0][0] + buf[1][0] + buf[2][0] + buf[3][0];
        ss = buf[0][1] + buf[1][1] + buf[2][1] + buf[3][1];
        buf[0][0] = s; buf[0][1] = ss;
    }
    __syncthreads();
    s = buf[0][0]; ss = buf[0][1];

    float invC = 1.f / (float)C;
    float mu = s * invC;
    float var = ss * invC - mu * mu;
    float inv = rsqrtf(var + 1e-5f);
    const float4* gg = (const float4*)g;
    const float4* bb = (const float4*)b;
    for (int i = threadIdx.x; i < C8; i += 256) {
        uint4 raw = xr[i];
        const __hip_bfloat16* p = (const __hip_bfloat16*)&raw;
        float4 g0 = gg[2 * i], g1 = gg[2 * i + 1];
        float4 b0 = bb[2 * i], b1 = bb[2 * i + 1];
        __hip_bfloat16 t[8];
        t[0] = __float2bfloat16((__bfloat162float(p[0]) - mu) * inv * g0.x + b0.x);
        t[1] = __float2bfloat16((__bfloat162float(p[1]) - mu) * inv * g0.y + b0.y);
        t[2] = __float2bfloat16((__bfloat162float(p[2]) - mu) * inv * g0.z + b0.z);
        t[3] = __float2bfloat16((__bfloat162float(p[3]) - mu) * inv * g0.w + b0.w);
        t[4] = __float2bfloat16((__bfloat162float(p[4]) - mu) * inv * g1.x + b1.x);
        t[5] = __float2bfloat16((__bfloat162float(p[5]) - mu) * inv * g1.y + b1.y);
        t[6] = __float2bfloat16((__bfloat162float(p[6]) - mu) * inv * g1.z + b1.z);
        t[7] = __float2bfloat16((__bfloat162float(p[7]) - mu) * inv * g1.w + b1.w);
        yr[i] = *(uint4*)t;
    }
}

// ---------------- gemm8p: 256x256 tile, counted-vmcnt phased schedule ------
// C = A[M,K] @ W[N,K]^T. 512 thr = 8 waves (wm = wave>>2 in {0,1} -> 128 rows,
// wn = wave&3 -> 64 cols). acc[8][4]. K-tile = 64, 2 phases (kh halves).
// LDS [2 buf][2 mat][2 kh][256 rows x 64 B] = 128 KB. Chunk swizzle:
// phys_chunk = log_chunk ^ ((row>>1)&3); source pre-swizzled (rule 21).
// Per phase each wave issues exactly 4 gl_lds; phase-end s_waitcnt vmcnt(4)
// certifies the next phase's slab, then raw s_barrier. Tail vmcnt(0).
// mode 0: bf16 out (+bias if non-null). mode 1: bf16 out, bias+gelu.
__global__ __launch_bounds__(512, 2) void gemm8p(
    const __hip_bfloat16* __restrict__ A,
    const __hip_bfloat16* __restrict__ W,
    const float* __restrict__ bias,
    __hip_bfloat16* __restrict__ Cout, int M, int N, int K, int mode)
{
    __shared__ __align__(16) char Lds[2][2][2][16384];  // [buf][A/B][kh][slab]

    const int tid = threadIdx.x;
    const int wave = tid >> 6, lane = tid & 63;
    const int fm = lane & 15, quad = lane >> 4;

    int mt, nt;
    {
        int gx = gridDim.x, gy = gridDim.y;
        int lin = blockIdx.y * gx + blockIdx.x;
        int chunk = gy >> 3;                 // gy = 16 in all uses
        int xcd = lin & 7, q = lin >> 3;
        mt = xcd * chunk + (q % chunk);
        nt = q / chunk;
    }
    const int bm = mt * 256, bn = nt * 256;
    const int wm = wave >> 2, wn = wave & 3;

    const int nk = K / 64;

    // ---- staging addresses (per lane) ----
    // issue covers 128 rows (8 waves x 16); lane l -> row wave*16 + (l>>2),
    // phys chunk l&3 holds logical chunk (l&3)^((l>>3)&3).
    const int clog = (lane & 3) ^ ((lane >> 3) & 3);
    const int srow = wave * 16 + (lane >> 2);
    const __hip_bfloat16* gAb = A + (long)(bm + srow) * K + clog * 8;
    const __hip_bfloat16* gBb = W + (long)(bn + srow) * K + clog * 8;
    const long rK = (long)128 * K;
    const int ldst = wave * 1024;            // wave-uniform dst offset in slab

#define STAGE8(b, kt, h) { \
    const long go = (long)(kt) * 64 + (h) * 32; \
    gl_lds16(gAb + go,      &Lds[b][0][h][ldst]); \
    gl_lds16(gAb + rK + go, &Lds[b][0][h][8192 + ldst]); \
    gl_lds16(gBb + go,      &Lds[b][1][h][ldst]); \
    gl_lds16(gBb + rK + go, &Lds[b][1][h][8192 + ldst]); }

    // ---- frag-read offset (swizzled): row fm within frag, chunk quad ----
    const int rdoff = fm * 64 + ((quad ^ ((fm >> 1) & 3)) << 4);

    floatx4 acc[8][4] = {};

    // prologue: stage T0 fully; certify h0; barrier.
    STAGE8(0, 0, 0);
    STAGE8(0, 0, 1);
    asm volatile("s_waitcnt vmcnt(4)" ::: "memory");
    __builtin_amdgcn_s_barrier();
    __builtin_amdgcn_sched_barrier(0);

    #pragma unroll 1
    for (int t = 0; t < nk; ++t) {
        const int c = t & 1;
        #pragma unroll
        for (int h = 0; h < 2; ++h) {
            if (t + 1 < nk) STAGE8(c ^ 1, t + 1, h);

            const char* As = Lds[c][0][h];
            const char* Bs = Lds[c][1][h];
            short8 bq[4];
            #pragma unroll
            for (int j = 0; j < 4; ++j)
                bq[j] = *(const short8*)(Bs + (wn * 64 + j * 16) * 64 + rdoff);

            __builtin_amdgcn_s_setprio(1);
            #pragma unroll
            for (int i = 0; i < 8; ++i) {
                short8 af = *(const short8*)(As + (wm * 128 + i * 16) * 64 + rdoff);
                #pragma unroll
                for (int j = 0; j < 4; ++j)
                    acc[i][j] = __builtin_amdgcn_mfma_f32_16x16x32_bf16(
                        af, bq[j], acc[i][j], 0, 0, 0);
            }
            __builtin_amdgcn_s_setprio(0);

            // phase-end: certify next phase's slab (own slice), then barrier.
            if (t + 1 < nk) {
                asm volatile("s_waitcnt vmcnt(4)" ::: "memory");
            } else if (h == 0) {
                asm volatile("s_waitcnt vmcnt(0)" ::: "memory");
            }
            __builtin_amdgcn_s_barrier();
            __builtin_amdgcn_sched_barrier(0);
        }
    }
#undef STAGE8

    // ---- epilogue ----
    const int mbase = bm + wm * 128;
    const int nbase = bn + wn * 64;
    #pragma unroll
    for (int i = 0; i < 8; ++i) {
        #pragma unroll
        for (int j = 0; j < 4; ++j) {
            int ncol = nbase + j * 16 + fm;
            #pragma unroll
            for (int r = 0; r < 4; ++r) {
                int mrow = mbase + i * 16 + quad * 4 + r;
                float v = acc[i][j][r];
                if (bias) v += bias[ncol];
                if (mode == 1) {
                    float z = v * (1.5957691216f + 0.0713548162f * v * v);
                    v = v / (1.f + __expf(-z));
                }
                Cout[(long)mrow * N + ncol] = __float2bfloat16(v);
            }
        }
    }
}

// ---------------- gemm_db<BK>: 128x128 tile, dbuf gl_lds, swizzled ---------
// (R12, passing) -- used for proj & fc2 with BK=128.
template<int BK>
__global__ __launch_bounds__(256, BK == 64 ? 2 : 1) void gemm_db(
    const __hip_bfloat16* __restrict__ A,
    const __hip_bfloat16* __restrict__ W,
    const float* __restrict__ bias, const float* __restrict__ residual,
    void* __restrict__ Cout, int M, int N, int K, int mode)
{
    constexpr int ROWSEG = 512 / BK;     // rows per 1KB staging segment
    constexpr int CHK    = BK / 8;       // 16B chunks per row
    constexpr int MASK   = CHK - 1;
    constexpr int NSEGW  = BK / 16;      // segments per wave (per matrix)
    constexpr int RS     = 2 * BK;       // LDS row stride in bytes
    constexpr int KH     = BK / 32;      // K=32 groups per K-step

    __shared__ __align__(16) char Asl[2][BK * 256];   // 128 rows * BK * 2B
    __shared__ __align__(16) char Bsl[2][BK * 256];

    int tid = threadIdx.x;
    int wave = tid >> 6, lane = tid & 63;

    int mt, nt;
    {
        int gx = gridDim.x, gy = gridDim.y;
        int lin = blockIdx.y * gx + blockIdx.x;
        int chunk = gy >> 3;                 // gy = 32 in all uses
        int xcd = lin & 7, q = lin >> 3;
        mt = xcd * chunk + (q % chunk);
        nt = q / chunk;
    }
    int bm = mt * 128, bn = nt * 128;
    int wm = wave & 1, wn = wave >> 1;
    int fm = lane & 15, quad = lane >> 4;

    const int nk = K / BK;

    const int rsub  = lane / CHK;
    const int cphys = lane & MASK;
    const __hip_bfloat16* gA[NSEGW];
    const __hip_bfloat16* gB[NSEGW];
    int dseg[NSEGW];
    #pragma unroll
    for (int j = 0; j < NSEGW; ++j) {
        int seg = wave * NSEGW + j;
        int row = seg * ROWSEG + rsub;
        int csrc = cphys ^ (row & MASK);
        gA[j] = A + (long)(bm + row) * K + csrc * 8;
        gB[j] = W + (long)(bn + row) * K + csrc * 8;
        dseg[j] = seg * 1024;
    }

#define STAGE(b, kt) { \
    const long ko = (long)(kt) * BK; \
    _Pragma("unroll") \
    for (int j = 0; j < NSEGW; ++j) { \
        gl_lds16(gA[j] + ko, Asl[b] + dseg[j]); \
        gl_lds16(gB[j] + ko, Bsl[b] + dseg[j]); \
    } }

    floatx4 acc[4][4] = {};

    STAGE(0, 0);
    __syncthreads();   // vmcnt(0) drain inside

    int cur = 0;
    for (int kt = 0; kt < nk; ++kt) {
        if (kt + 1 < nk) STAGE(cur ^ 1, kt + 1);   // issue next tile loads

        const char* Ab = Asl[cur];
        const char* Bb = Bsl[cur];
        #pragma unroll
        for (int kh = 0; kh < KH; ++kh) {
            const int xsw = (((kh * 4 + quad) ^ (fm & MASK)) << 4);
            short8 bq[4];
            #pragma unroll
            for (int j = 0; j < 4; ++j)
                bq[j] = *(const short8*)(Bb + (wn * 64 + j * 16 + fm) * RS + xsw);
            #pragma unroll
            for (int i = 0; i < 4; ++i) {
                short8 af = *(const short8*)(Ab + (wm * 64 + i * 16 + fm) * RS + xsw);
                #pragma unroll
                for (int j = 0; j < 4; ++j)
                    acc[i][j] = __builtin_amdgcn_mfma_f32_16x16x32_bf16(
                        af, bq[j], acc[i][j], 0, 0, 0);
            }
        }
        __syncthreads();   // drains vmcnt (next tile arrived) + lgkm; barrier
        cur ^= 1;
    }
#undef STAGE

    int mbase = bm + wm * 64;
    int nbase = bn + wn * 64;
    if (mode == 2) {
        float* Cf = (float*)Cout;
        #pragma unroll
        for (int i = 0; i < 4; ++i) {
            #pragma unroll
            for (int j = 0; j < 4; ++j) {
                int ncol = nbase + j * 16 + fm;
                float bv = bias[ncol];
                #pragma unroll
                for (int r = 0; r < 4; ++r) {
                    int mrow = mbase + i * 16 + quad * 4 + r;
                    long idx = (long)mrow * N + ncol;
                    Cf[idx] = acc[i][j][r] + bv + residual[idx];
                }
            }
        }
    } else {
        __hip_bfloat16* Cb = (__hip_bfloat16*)Cout;
        #pragma unroll
        for (int i = 0; i < 4; ++i) {
            #pragma unroll
            for (int j = 0; j < 4; ++j) {
                int ncol = nbase + j * 16 + fm;
                #pragma unroll
                for (int r = 0; r < 4; ++r) {
                    int mrow = mbase + i * 16 + quad * 4 + r;
                    float v = acc[i][j][r];
                    if (bias) v += bias[ncol];
                    if (mode == 1) {
                        float z = v * (1.5957691216f + 0.0713548162f * v * v);
                        v = v / (1.f + __expf(-z));
                    }
                    Cb[(long)mrow * N + ncol] = __float2bfloat16(v);
                }
            }
        }
    }
}

// ---------------- MFMA flash attention, pipelined (R5, unchanged) ----------
__global__ __launch_bounds__(256) void attn_mfma(
    const __hip_bfloat16* __restrict__ qkv, __hip_bfloat16* __restrict__ o_out)
{
    __shared__ __align__(16) char Ks[2][64 * 144];
    __shared__ __align__(16) char Vt[2][64 * 144];
    __shared__ __align__(16) char Ps[4 * 16 * 144];

    const int C3 = 3 * CDIM;
    int lin = blockIdx.x;
    int xcd = lin & 7, q = lin >> 3;
    int bh = xcd * 8 + (q >> 4);
    int qt = q & 15;
    int b = bh >> 4, hh = bh & 15;
    int tid = threadIdx.x, wave = tid >> 6, lane = tid & 63;
    int l = lane & 15, quad = lane >> 4;

    const __hip_bfloat16* qrow =
        qkv + (long)(b * 1024 + qt * 64 + wave * 16 + l) * C3 + hh * DHEAD;
    short8 qf0 = *(const short8*)(qrow + quad * 8);
    short8 qf1 = *(const short8*)(qrow + 32 + quad * 8);

    char* Psw = Ps + wave * (16 * 144);

    int sc = tid & 7;
    int skl = tid >> 3;

    const __hip_bfloat16* Kbase = qkv + (long)(b * 1024) * C3 + CDIM + hh * DHEAD;
    const __hip_bfloat16* Vbase = qkv + (long)(b * 1024) * C3 + 2 * CDIM + hh * DHEAD;
    const int kpp = skl ^ (sc << 2);

    floatx4 facc[4] = {};
    float mrun = -1e30f, lrun = 0.f;

    uint4 kA0, kA1, vA0, vA1;
    uint4 kB0, kB1, vB0, vB1;

#define GKV(t, k0, k1, v0, v1) { \
    const __hip_bfloat16* Kg = Kbase + (long)((t) * 64) * C3; \
    const __hip_bfloat16* Vg = Vbase + (long)((t) * 64) * C3; \
    k0 = *(const uint4*)(Kg + (long)skl * C3 + sc * 8); \
    k1 = *(const uint4*)(Kg + (long)(skl + 32) * C3 + sc * 8); \
    v0 = *(const uint4*)(Vg + (long)(2 * skl) * C3 + sc * 8); \
    v1 = *(const uint4*)(Vg + (long)(2 * skl + 1) * C3 + sc * 8); }
#define WKV(bf, k0, k1, v0, v1) { \
    *(uint4*)(Ks[bf] + skl * 144 + sc * 16) = k0; \
    *(uint4*)(Ks[bf] + (skl + 32) * 144 + sc * 16) = k1; \
    const ushort* e0 = (const ushort*)&v0; \
    const ushort* e1 = (const ushort*)&v1; \
    _Pragma("unroll") \
    for (int j = 0; j < 8; ++j) { \
        unsigned dw = (unsigned)e0[j] | ((unsigned)e1[j] << 16); \
        *(unsigned*)(Vt[bf] + (sc * 8 + j) * 144 + kpp * 4) = dw; \
    } }

    auto compute = [&](int buf) {
        floatx4 st[4] = {};
        #pragma unroll
        for (int kb = 0; kb < 4; ++kb) {
            short8 k0 = *(const short8*)(Ks[buf] + (kb * 16 + l) * 144 + quad * 16);
            short8 k1 = *(const short8*)(Ks[buf] + (kb * 16 + l) * 144 + 64 + quad * 16);
            st[kb] = __builtin_amdgcn_mfma_f32_16x16x32_bf16(k0, qf0, st[kb], 0, 0, 0);
            st[kb] = __builtin_amdgcn_mfma_f32_16x16x32_bf16(k1, qf1, st[kb], 0, 0, 0);
        }
        float p[16];
        float tm = -1e30f;
        #pragma unroll
        for (int kb = 0; kb < 4; ++kb)
            #pragma unroll
            for (int r = 0; r < 4; ++r) {
                float s = st[kb][r] * 0.125f;
                p[kb * 4 + r] = s;
                tm = fmaxf(tm, s);
            }
        tm = fmaxf(tm, __shfl_xor(tm, 16));
        tm = fmaxf(tm, __shfl_xor(tm, 32));
        float mn = fmaxf(mrun, tm);
        float alpha = __expf(mrun - mn);
        float psum = 0.f;
        #pragma unroll
        for (int i = 0; i < 16; ++i) { p[i] = __expf(p[i] - mn); psum += p[i]; }
        psum += __shfl_xor(psum, 16);
        psum += __shfl_xor(psum, 32);
        lrun = lrun * alpha + psum;
        mrun = mn;

        #pragma unroll
        for (int kb = 0; kb < 4; ++kb) {
            __hip_bfloat16 t[4];
            #pragma unroll
            for (int r = 0; r < 4; ++r) t[r] = __float2bfloat16(p[kb * 4 + r]);
            *(uint2*)(Psw + l * 144 + kb * 32 + quad * 8) = *(const uint2*)t;
        }

        float a0 = __shfl(alpha, quad * 4 + 0);
        float a1 = __shfl(alpha, quad * 4 + 1);
        float a2 = __shfl(alpha, quad * 4 + 2);
        float a3 = __shfl(alpha, quad * 4 + 3);
        #pragma unroll
        for (int db = 0; db < 4; ++db) {
            facc[db][0] *= a0; facc[db][1] *= a1;
            facc[db][2] *= a2; facc[db][3] *= a3;
        }

        short8 pf0 = *(const short8*)(Psw + l * 144 + quad * 16);
        short8 pf1 = *(const short8*)(Psw + l * 144 + 64 + quad * 16);
        #pragma unroll
        for (int db = 0; db < 4; ++db) {
            int d = db * 16 + l;
            int o3 = (d >> 3) & 7;
            short8 v0 = *(const short8*)(Vt[buf] + d * 144 + ((quad ^ o3) << 4));
            short8 v1 = *(const short8*)(Vt[buf] + d * 144 + (((4 + quad) ^ o3) << 4));
            facc[db] = __builtin_amdgcn_mfma_f32_16x16x32_bf16(pf0, v0, facc[db], 0, 0, 0);
            facc[db] = __builtin_amdgcn_mfma_f32_16x16x32_bf16(pf1, v1, facc[db], 0, 0, 0);
        }
    };

    GKV(0, kA0, kA1, vA0, vA1);
    #pragma unroll 1
    for (int kt = 0; kt < 16; kt += 2) {
        WKV(0, kA0, kA1, vA0, vA1);
        __syncthreads();
        GKV(kt + 1, kB0, kB1, vB0, vB1);
        compute(0);
        WKV(1, kB0, kB1, vB0, vB1);
        __syncthreads();
        if (kt + 2 < 16) GKV(kt + 2, kA0, kA1, vA0, vA1);
        compute(1);
    }
#undef GKV
#undef WKV

    float il0 = 1.f / __shfl(lrun, quad * 4 + 0);
    float il1 = 1.f / __shfl(lrun, quad * 4 + 1);
    float il2 = 1.f / __shfl(lrun, quad * 4 + 2);
    float il3 = 1.f / __shfl(lrun, quad * 4 + 3);
    __hip_bfloat16* orow =
        o_out + (long)(b * 1024 + qt * 64 + wave * 16) * CDIM + hh * DHEAD;
    #pragma unroll
    for (int db = 0; db < 4; ++db) {
        int col = db * 16 + l;
        orow[(quad * 4 + 0) * CDIM + col] = __float2bfloat16(facc[db][0] * il0);
        orow[(quad * 4 + 1) * CDIM + col] = __float2bfloat16(facc[db][1] * il1);
        orow[(quad * 4 + 2) * CDIM + col] = __float2bfloat16(facc[db][2] * il2);
        orow[(quad * 4 + 3) * CDIM + col] = __float2bfloat16(facc[db][3] * il3);
    }
}

// ---------------------------------------------------------------------------
extern "C" void kernel_launch(void* const* d_in, const int* in_sizes, int n_in,
                              void* d_out, int out_size, void* d_ws, size_t ws_size,
                              hipStream_t stream)
{
    const float* x      = (const float*)d_in[0];
    const float* qkv_w  = (const float*)d_in[1];
    const float* proj_w = (const float*)d_in[2];
    const float* proj_b = (const float*)d_in[3];
    const float* fc1_w  = (const float*)d_in[4];
    const float* fc1_b  = (const float*)d_in[5];
    const float* fc2_w  = (const float*)d_in[6];
    const float* fc2_b  = (const float*)d_in[7];
    const float* ln1_g  = (const float*)d_in[8];
    const float* ln1_b  = (const float*)d_in[9];
    const float* ln2_g  = (const float*)d_in[10];
    const float* ln2_b  = (const float*)d_in[11];
    const float* lnh_g  = (const float*)d_in[12];
    const float* lnh_b  = (const float*)d_in[13];

    float* out = (float*)d_out;

    __hip_bfloat16* wsb     = (__hip_bfloat16*)d_ws;
    __hip_bfloat16* qkvw_bf = wsb;
    __hip_bfloat16* fc1w_bf = qkvw_bf + 3l * 1024 * 1024;
    __hip_bfloat16* fc2w_bf = fc1w_bf + 4l * 1024 * 1024;
    __hip_bfloat16* projw_bf= fc2w_bf + 4l * 1024 * 1024;
    __hip_bfloat16* h_bf    = projw_bf + 1l * 1024 * 1024;
    __hip_bfloat16* qkv_bf  = h_bf + 4l * 1024 * 1024;
    __hip_bfloat16* o_bf    = qkv_bf + 12l * 1024 * 1024;
    __hip_bfloat16* u_bf    = o_bf + 4l * 1024 * 1024;

    // 0. all weights fp32 -> bf16
    cvt_all<<<12288, 256, 0, stream>>>(qkv_w, fc1_w, fc2_w, proj_w, qkvw_bf);

    // 1. h = LN1(x)
    ln_f32_kernel<<<TOKENS, 256, 0, stream>>>(x, ln1_g, ln1_b, h_bf, CDIM);
    // 2. qkv = h @ qkv_w^T  (256^2 tiles: 12x16 = 192 blocks)
    gemm8p<<<dim3(3072 / 256, TOKENS / 256), 512, 0, stream>>>(
        h_bf, qkvw_bf, nullptr, qkv_bf, TOKENS, 3072, CDIM, 0);
    // 3. o = attention(qkv)
    attn_mfma<<<1024, 256, 0, stream>>>(qkv_bf, o_bf);
    // 4. out = x + o @ proj_w^T + proj_b  (gemm_db BK=128, passing)
    gemm_db<128><<<dim3(CDIM / 128, TOKENS / 128), 256, 0, stream>>>(
        o_bf, projw_bf, proj_b, x, out, TOKENS, CDIM, CDIM, 2);
    // 5. h2 = LN2(out)
    ln_f32_kernel<<<TOKENS, 256, 0, stream>>>(out, ln2_g, ln2_b, h_bf, CDIM);
    // 6. u = gelu(h2 @ fc1_w^T + fc1_b)  (256^2 tiles: 16x16 = 256 blocks)
    gemm8p<<<dim3(HID / 256, TOKENS / 256), 512, 0, stream>>>(
        h_bf, fc1w_bf, fc1_b, u_bf, TOKENS, HID, CDIM, 1);
    // 7. u = LNh(u) in place
    ln_bf16_kernel<<<TOKENS, 256, 0, stream>>>(u_bf, lnh_g, lnh_b, u_bf, HID);
    // 8. out = out + u @ fc2_w^T + fc2_b  (gemm_db BK=128, passing)
    gemm_db<128><<<dim3(CDIM / 128, TOKENS / 128), 256, 0, stream>>>(
        u_bf, fc2w_bf, fc2_b, out, out, TOKENS, CDIM, HID, 2);
}

// Round 7
// 344.620 us; speedup vs baseline: 1.1220x; 1.0389x over previous
//
#include <hip/hip_runtime.h>
#include <hip/hip_bf16.h>
#include <math.h>

// ---------------------------------------------------------------------------
// Transformer block. R15: maximize blocks/CU (the m97/m114 lever).
//  All session GEMM variants (1-2 blocks/CU) converge to ~60-70us, ~20%
//  MfmaUtil, all pipes idle -> intra-block serialization with no co-resident
//  blocks to hide it. Fix: 32 KB LDS GEMMs -> 4-5 blocks/CU.
//  - gemm32q (qkv, fc1): 128x128 tile, BK=32, quad-packed LDS: 64 rows x
//    128 B per matrix per buffer (two M-halves share a row; chunk bit2 =
//    M-half). 8-chunk XOR swizzle (measured 0 conflicts in R11-R14).
//    4 waves 2x2, 16 ds_read + 16 MFMA per K-step. 32 KB LDS.
//  - gemm64g (proj, fc2): 64x64 tile, BK=64, 64 rows x 128 B, same swizzle.
//    Grid (N/64, M/64) = 1024 blocks = 4/CU -- breaks fc2's grid cap
//    without split-K atomics. f32 + bias + residual epilogue.
//  - LN / attention / cvt unchanged. gemm8p dropped (21% MfmaUtil ~= dbuf).
// ---------------------------------------------------------------------------

#define TOKENS 4096
#define CDIM   1024
#define HEADS  16
#define DHEAD  64
#define HID    4096

typedef __attribute__((ext_vector_type(4))) float  floatx4;
typedef __attribute__((ext_vector_type(8))) short  short8;  // 8 x bf16 frag

// async global -> LDS, 16 bytes per lane. LDS dst is the WAVE-UNIFORM base;
// HW writes lane i's 16B at (base + i*16). Global src is per-lane.
__device__ __forceinline__ void gl_lds16(const void* g, void* l)
{
    __builtin_amdgcn_global_load_lds(
        (const __attribute__((address_space(1))) unsigned int*)g,
        (__attribute__((address_space(3))) unsigned int*)l,
        16, 0, 0);
}

// ---------------- fused fp32 -> bf16 weight convert ----------------
__global__ __launch_bounds__(256) void cvt_all(
    const float* __restrict__ s0, const float* __restrict__ s1,
    const float* __restrict__ s2, const float* __restrict__ s3,
    __hip_bfloat16* __restrict__ dst)
{
    long i = (long)blockIdx.x * 256 + threadIdx.x;   // float4 index, 3M total
    const float* src;
    long base;
    if (i < 768l * 1024)       { src = s0; base = 0; }
    else if (i < 1792l * 1024) { src = s1; base = 768l * 1024; }
    else if (i < 2816l * 1024) { src = s2; base = 1792l * 1024; }
    else                       { src = s3; base = 2816l * 1024; }
    float4 v = ((const float4*)src)[i - base];
    __hip_bfloat16 t[4];
    t[0] = __float2bfloat16(v.x);
    t[1] = __float2bfloat16(v.y);
    t[2] = __float2bfloat16(v.z);
    t[3] = __float2bfloat16(v.w);
    *(uint2*)(dst + 4l * i) = *(uint2*)t;
}

// ---------------- LayerNorm: fp32 in -> bf16 out (vectorized) --------------
__global__ __launch_bounds__(256) void ln_f32_kernel(
    const float* __restrict__ x, const float* __restrict__ g,
    const float* __restrict__ b, __hip_bfloat16* __restrict__ y, int C)
{
    int row = blockIdx.x;
    const float4* xr = (const float4*)(x + (long)row * C);
    uint2* yr = (uint2*)(y + (long)row * C);
    const int C4 = C >> 2;

    float s = 0.f, ss = 0.f;
    for (int i = threadIdx.x; i < C4; i += 256) {
        float4 v = xr[i];
        s  += v.x + v.y + v.z + v.w;
        ss += v.x * v.x + v.y * v.y + v.z * v.z + v.w * v.w;
    }
    #pragma unroll
    for (int d = 32; d; d >>= 1) {
        s  += __shfl_down(s, d);
        ss += __shfl_down(ss, d);
    }
    __shared__ float buf[4][2];
    int wid = threadIdx.x >> 6, lane = threadIdx.x & 63;
    if (lane == 0) { buf[wid][0] = s; buf[wid][1] = ss; }
    __syncthreads();
    if (threadIdx.x == 0) {
        s = buf[0][0] + buf[1][0] + buf[2][0] + buf[3][0];
        ss = buf[0][1] + buf[1][1] + buf[2][1] + buf[3][1];
        buf[0][0] = s; buf[0][1] = ss;
    }
    __syncthreads();
    s = buf[0][0]; ss = buf[0][1];

    float invC = 1.f / (float)C;
    float mu = s * invC;
    float var = ss * invC - mu * mu;
    float inv = rsqrtf(var + 1e-5f);
    const float4* gg = (const float4*)g;
    const float4* bb = (const float4*)b;
    for (int i = threadIdx.x; i < C4; i += 256) {
        float4 v = xr[i], gv = gg[i], bv = bb[i];
        __hip_bfloat16 t[4];
        t[0] = __float2bfloat16((v.x - mu) * inv * gv.x + bv.x);
        t[1] = __float2bfloat16((v.y - mu) * inv * gv.y + bv.y);
        t[2] = __float2bfloat16((v.z - mu) * inv * gv.z + bv.z);
        t[3] = __float2bfloat16((v.w - mu) * inv * gv.w + bv.w);
        yr[i] = *(uint2*)t;
    }
}

// ---------------- LayerNorm: bf16 in -> bf16 out (vectorized, in place ok) --
__global__ __launch_bounds__(256) void ln_bf16_kernel(
    const __hip_bfloat16* __restrict__ x, const float* __restrict__ g,
    const float* __restrict__ b, __hip_bfloat16* __restrict__ y, int C)
{
    int row = blockIdx.x;
    const uint4* xr = (const uint4*)(x + (long)row * C);
    uint4* yr = (uint4*)(y + (long)row * C);
    const int C8 = C >> 3;

    float s = 0.f, ss = 0.f;
    for (int i = threadIdx.x; i < C8; i += 256) {
        uint4 raw = xr[i];
        const __hip_bfloat16* p = (const __hip_bfloat16*)&raw;
        #pragma unroll
        for (int j = 0; j < 8; ++j) {
            float v = __bfloat162float(p[j]);
            s += v; ss += v * v;
        }
    }
    #pragma unroll
    for (int d = 32; d; d >>= 1) {
        s  += __shfl_down(s, d);
        ss += __shfl_down(ss, d);
    }
    __shared__ float buf[4][2];
    int wid = threadIdx.x >> 6, lane = threadIdx.x & 63;
    if (lane == 0) { buf[wid][0] = s; buf[wid][1] = ss; }
    __syncthreads();
    if (threadIdx.x == 0) {
        s = buf[0][0] + buf[1][0] + buf[2][0] + buf[3][0];
        ss = buf[0][1] + buf[1][1] + buf[2][1] + buf[3][1];
        buf[0][0] = s; buf[0][1] = ss;
    }
    __syncthreads();
    s = buf[0][0]; ss = buf[0][1];

    float invC = 1.f / (float)C;
    float mu = s * invC;
    float var = ss * invC - mu * mu;
    float inv = rsqrtf(var + 1e-5f);
    const float4* gg = (const float4*)g;
    const float4* bb = (const float4*)b;
    for (int i = threadIdx.x; i < C8; i += 256) {
        uint4 raw = xr[i];
        const __hip_bfloat16* p = (const __hip_bfloat16*)&raw;
        float4 g0 = gg[2 * i], g1 = gg[2 * i + 1];
        float4 b0 = bb[2 * i], b1 = bb[2 * i + 1];
        __hip_bfloat16 t[8];
        t[0] = __float2bfloat16((__bfloat162float(p[0]) - mu) * inv * g0.x + b0.x);
        t[1] = __float2bfloat16((__bfloat162float(p[1]) - mu) * inv * g0.y + b0.y);
        t[2] = __float2bfloat16((__bfloat162float(p[2]) - mu) * inv * g0.z + b0.z);
        t[3] = __float2bfloat16((__bfloat162float(p[3]) - mu) * inv * g0.w + b0.w);
        t[4] = __float2bfloat16((__bfloat162float(p[4]) - mu) * inv * g1.x + b1.x);
        t[5] = __float2bfloat16((__bfloat162float(p[5]) - mu) * inv * g1.y + b1.y);
        t[6] = __float2bfloat16((__bfloat162float(p[6]) - mu) * inv * g1.z + b1.z);
        t[7] = __float2bfloat16((__bfloat162float(p[7]) - mu) * inv * g1.w + b1.w);
        yr[i] = *(uint4*)t;
    }
}

// ---------------- gemm32q: 128x128 tile, BK=32, quad-packed 32KB LDS -------
// C = A[M,K] @ W[N,K]^T. 256 thr = 4 waves 2x2, wave tile 64x64, acc[4][4].
// LDS per matrix per buffer: 64 rows x 128 B (8 KB). Logical layout:
//   LDS(row r, chunk c_phys) holds A[Mrow][k0..k0+7] where
//   c_log = c_phys ^ (r & 7), Mrow = r + 64*(c_log>>2), k0 = (c_log&3)*8.
// Read frag (Mrow = wm*64+i*16+fm, kchunk = quad): row = i*16+fm,
//   c_phys = (wm*4+quad) ^ (fm&7) -> 8 distinct 16B slots, 2 lanes/bank =
//   conflict-free (same pattern measured 0 conflicts R11-R14).
// Staging: 8 segs/matrix (1 KB = 8 rows); wave stages segs wave*2+{0,1};
//   lane -> ldsrow seg*8+(lane>>3), c_phys lane&7, source addr derived from
//   the inverse mapping above. 4 gl_lds/thread/K-step.
// mode 0: bf16 out (+bias if non-null). mode 1: bf16 out, bias+gelu.
__global__ __launch_bounds__(256, 4) void gemm32q(
    const __hip_bfloat16* __restrict__ A,
    const __hip_bfloat16* __restrict__ W,
    const float* __restrict__ bias,
    __hip_bfloat16* __restrict__ Cout, int M, int N, int K, int mode)
{
    __shared__ __align__(16) char Asl[2][8192];
    __shared__ __align__(16) char Bsl[2][8192];

    int tid = threadIdx.x;
    int wave = tid >> 6, lane = tid & 63;

    int mt, nt;
    {
        int gx = gridDim.x, gy = gridDim.y;
        int lin = blockIdx.y * gx + blockIdx.x;
        int chunk = gy >> 3;                 // gy % 8 == 0 in all uses
        int xcd = lin & 7, q = lin >> 3;
        mt = xcd * chunk + (q % chunk);
        nt = q / chunk;
    }
    int bm = mt * 128, bn = nt * 128;
    int wm = wave & 1, wn = wave >> 1;
    int fm = lane & 15, quad = lane >> 4;

    const int nk = K / 32;

    // staging addresses (inverse of the packed layout)
    const int rsub  = lane >> 3;             // 0..7 (row within segment)
    const int cphys = lane & 7;
    const int clog  = cphys ^ rsub;          // ldsrow&7 == rsub
    const __hip_bfloat16* gA[2];
    const __hip_bfloat16* gB[2];
    int dseg[2];
    #pragma unroll
    for (int j = 0; j < 2; ++j) {
        int seg = wave * 2 + j;
        int ldsrow = seg * 8 + rsub;
        int mrow = ldsrow + 64 * (clog >> 2);
        int koff = (clog & 3) * 8;
        gA[j] = A + (long)(bm + mrow) * K + koff;
        gB[j] = W + (long)(bn + mrow) * K + koff;
        dseg[j] = seg * 1024;
    }

#define STAGE(b, kt) { \
    const long ko = (long)(kt) * 32; \
    _Pragma("unroll") \
    for (int j = 0; j < 2; ++j) { \
        gl_lds16(gA[j] + ko, Asl[b] + dseg[j]); \
        gl_lds16(gB[j] + ko, Bsl[b] + dseg[j]); \
    } }

    floatx4 acc[4][4] = {};

    STAGE(0, 0);
    __syncthreads();

    const int xswA = (((wm * 4 + quad) ^ (fm & 7)) << 4);
    const int xswB = (((wn * 4 + quad) ^ (fm & 7)) << 4);

    int cur = 0;
    for (int kt = 0; kt < nk; ++kt) {
        if (kt + 1 < nk) STAGE(cur ^ 1, kt + 1);

        const char* Ab = Asl[cur];
        const char* Bb = Bsl[cur];
        short8 bq[4];
        #pragma unroll
        for (int j = 0; j < 4; ++j)
            bq[j] = *(const short8*)(Bb + (j * 16 + fm) * 128 + xswB);
        #pragma unroll
        for (int i = 0; i < 4; ++i) {
            short8 af = *(const short8*)(Ab + (i * 16 + fm) * 128 + xswA);
            #pragma unroll
            for (int j = 0; j < 4; ++j)
                acc[i][j] = __builtin_amdgcn_mfma_f32_16x16x32_bf16(
                    af, bq[j], acc[i][j], 0, 0, 0);
        }
        __syncthreads();
        cur ^= 1;
    }
#undef STAGE

    int mbase = bm + wm * 64;
    int nbase = bn + wn * 64;
    #pragma unroll
    for (int i = 0; i < 4; ++i) {
        #pragma unroll
        for (int j = 0; j < 4; ++j) {
            int ncol = nbase + j * 16 + fm;
            #pragma unroll
            for (int r = 0; r < 4; ++r) {
                int mrow = mbase + i * 16 + quad * 4 + r;
                float v = acc[i][j][r];
                if (bias) v += bias[ncol];
                if (mode == 1) {
                    float z = v * (1.5957691216f + 0.0713548162f * v * v);
                    v = v / (1.f + __expf(-z));
                }
                Cout[(long)mrow * N + ncol] = __float2bfloat16(v);
            }
        }
    }
}

// ---------------- gemm64g: 64x64 tile, BK=64, 32KB LDS, 4 blocks/CU --------
// C = A[M,K] @ W[N,K]^T + bias + residual (f32 out). 4 waves 2x2, wave 32x32.
// LDS per matrix per buffer: 64 rows x 128 B. Standard 8-chunk XOR swizzle
// (phys = logical ^ (row&7)), source pre-swizzled. Grid (N/64, M/64) = 1024
// blocks for proj/fc2 -> 4 blocks/CU.
__global__ __launch_bounds__(256, 4) void gemm64g(
    const __hip_bfloat16* __restrict__ A,
    const __hip_bfloat16* __restrict__ W,
    const float* __restrict__ bias, const float* __restrict__ residual,
    float* __restrict__ Cout, int M, int N, int K)
{
    __shared__ __align__(16) char Asl[2][8192];
    __shared__ __align__(16) char Bsl[2][8192];

    int tid = threadIdx.x;
    int wave = tid >> 6, lane = tid & 63;

    int mt, nt;
    {
        int gx = gridDim.x, gy = gridDim.y;
        int lin = blockIdx.y * gx + blockIdx.x;
        int chunk = gy >> 3;                 // gy = 64 -> 8
        int xcd = lin & 7, q = lin >> 3;
        mt = xcd * chunk + (q % chunk);
        nt = q / chunk;
    }
    int bm = mt * 64, bn = nt * 64;
    int wm = wave & 1, wn = wave >> 1;
    int fm = lane & 15, quad = lane >> 4;

    const int nk = K / 64;

    const int rsub = lane >> 3;              // 0..7
    const int csrc = (lane & 7) ^ rsub;      // pre-swizzled source chunk
    const __hip_bfloat16* gA[2];
    const __hip_bfloat16* gB[2];
    int dseg[2];
    #pragma unroll
    for (int j = 0; j < 2; ++j) {
        int seg = wave * 2 + j;
        int row = seg * 8 + rsub;            // row&7 == rsub
        gA[j] = A + (long)(bm + row) * K + csrc * 8;
        gB[j] = W + (long)(bn + row) * K + csrc * 8;
        dseg[j] = seg * 1024;
    }

#define STAGE(b, kt) { \
    const long ko = (long)(kt) * 64; \
    _Pragma("unroll") \
    for (int j = 0; j < 2; ++j) { \
        gl_lds16(gA[j] + ko, Asl[b] + dseg[j]); \
        gl_lds16(gB[j] + ko, Bsl[b] + dseg[j]); \
    } }

    floatx4 acc[2][2] = {};

    STAGE(0, 0);
    __syncthreads();

    int cur = 0;
    for (int kt = 0; kt < nk; ++kt) {
        if (kt + 1 < nk) STAGE(cur ^ 1, kt + 1);

        const char* Ab = Asl[cur];
        const char* Bb = Bsl[cur];
        #pragma unroll
        for (int kh = 0; kh < 2; ++kh) {
            const int xsw = (((kh * 4 + quad) ^ (fm & 7)) << 4);
            short8 b0 = *(const short8*)(Bb + (wn * 32 + fm) * 128 + xsw);
            short8 b1 = *(const short8*)(Bb + (wn * 32 + 16 + fm) * 128 + xsw);
            short8 a0 = *(const short8*)(Ab + (wm * 32 + fm) * 128 + xsw);
            short8 a1 = *(const short8*)(Ab + (wm * 32 + 16 + fm) * 128 + xsw);
            acc[0][0] = __builtin_amdgcn_mfma_f32_16x16x32_bf16(a0, b0, acc[0][0], 0, 0, 0);
            acc[0][1] = __builtin_amdgcn_mfma_f32_16x16x32_bf16(a0, b1, acc[0][1], 0, 0, 0);
            acc[1][0] = __builtin_amdgcn_mfma_f32_16x16x32_bf16(a1, b0, acc[1][0], 0, 0, 0);
            acc[1][1] = __builtin_amdgcn_mfma_f32_16x16x32_bf16(a1, b1, acc[1][1], 0, 0, 0);
        }
        __syncthreads();
        cur ^= 1;
    }
#undef STAGE

    int mbase = bm + wm * 32;
    int nbase = bn + wn * 32;
    #pragma unroll
    for (int i = 0; i < 2; ++i) {
        #pragma unroll
        for (int j = 0; j < 2; ++j) {
            int ncol = nbase + j * 16 + fm;
            float bv = bias[ncol];
            #pragma unroll
            for (int r = 0; r < 4; ++r) {
                int mrow = mbase + i * 16 + quad * 4 + r;
                long idx = (long)mrow * N + ncol;
                Cout[idx] = acc[i][j][r] + bv + residual[idx];
            }
        }
    }
}

// ---------------- MFMA flash attention, pipelined (R5, unchanged) ----------
__global__ __launch_bounds__(256) void attn_mfma(
    const __hip_bfloat16* __restrict__ qkv, __hip_bfloat16* __restrict__ o_out)
{
    __shared__ __align__(16) char Ks[2][64 * 144];
    __shared__ __align__(16) char Vt[2][64 * 144];
    __shared__ __align__(16) char Ps[4 * 16 * 144];

    const int C3 = 3 * CDIM;
    int lin = blockIdx.x;
    int xcd = lin & 7, q = lin >> 3;
    int bh = xcd * 8 + (q >> 4);
    int qt = q & 15;
    int b = bh >> 4, hh = bh & 15;
    int tid = threadIdx.x, wave = tid >> 6, lane = tid & 63;
    int l = lane & 15, quad = lane >> 4;

    const __hip_bfloat16* qrow =
        qkv + (long)(b * 1024 + qt * 64 + wave * 16 + l) * C3 + hh * DHEAD;
    short8 qf0 = *(const short8*)(qrow + quad * 8);
    short8 qf1 = *(const short8*)(qrow + 32 + quad * 8);

    char* Psw = Ps + wave * (16 * 144);

    int sc = tid & 7;
    int skl = tid >> 3;

    const __hip_bfloat16* Kbase = qkv + (long)(b * 1024) * C3 + CDIM + hh * DHEAD;
    const __hip_bfloat16* Vbase = qkv + (long)(b * 1024) * C3 + 2 * CDIM + hh * DHEAD;
    const int kpp = skl ^ (sc << 2);

    floatx4 facc[4] = {};
    float mrun = -1e30f, lrun = 0.f;

    uint4 kA0, kA1, vA0, vA1;
    uint4 kB0, kB1, vB0, vB1;

#define GKV(t, k0, k1, v0, v1) { \
    const __hip_bfloat16* Kg = Kbase + (long)((t) * 64) * C3; \
    const __hip_bfloat16* Vg = Vbase + (long)((t) * 64) * C3; \
    k0 = *(const uint4*)(Kg + (long)skl * C3 + sc * 8); \
    k1 = *(const uint4*)(Kg + (long)(skl + 32) * C3 + sc * 8); \
    v0 = *(const uint4*)(Vg + (long)(2 * skl) * C3 + sc * 8); \
    v1 = *(const uint4*)(Vg + (long)(2 * skl + 1) * C3 + sc * 8); }
#define WKV(bf, k0, k1, v0, v1) { \
    *(uint4*)(Ks[bf] + skl * 144 + sc * 16) = k0; \
    *(uint4*)(Ks[bf] + (skl + 32) * 144 + sc * 16) = k1; \
    const ushort* e0 = (const ushort*)&v0; \
    const ushort* e1 = (const ushort*)&v1; \
    _Pragma("unroll") \
    for (int j = 0; j < 8; ++j) { \
        unsigned dw = (unsigned)e0[j] | ((unsigned)e1[j] << 16); \
        *(unsigned*)(Vt[bf] + (sc * 8 + j) * 144 + kpp * 4) = dw; \
    } }

    auto compute = [&](int buf) {
        floatx4 st[4] = {};
        #pragma unroll
        for (int kb = 0; kb < 4; ++kb) {
            short8 k0 = *(const short8*)(Ks[buf] + (kb * 16 + l) * 144 + quad * 16);
            short8 k1 = *(const short8*)(Ks[buf] + (kb * 16 + l) * 144 + 64 + quad * 16);
            st[kb] = __builtin_amdgcn_mfma_f32_16x16x32_bf16(k0, qf0, st[kb], 0, 0, 0);
            st[kb] = __builtin_amdgcn_mfma_f32_16x16x32_bf16(k1, qf1, st[kb], 0, 0, 0);
        }
        float p[16];
        float tm = -1e30f;
        #pragma unroll
        for (int kb = 0; kb < 4; ++kb)
            #pragma unroll
            for (int r = 0; r < 4; ++r) {
                float s = st[kb][r] * 0.125f;
                p[kb * 4 + r] = s;
                tm = fmaxf(tm, s);
            }
        tm = fmaxf(tm, __shfl_xor(tm, 16));
        tm = fmaxf(tm, __shfl_xor(tm, 32));
        float mn = fmaxf(mrun, tm);
        float alpha = __expf(mrun - mn);
        float psum = 0.f;
        #pragma unroll
        for (int i = 0; i < 16; ++i) { p[i] = __expf(p[i] - mn); psum += p[i]; }
        psum += __shfl_xor(psum, 16);
        psum += __shfl_xor(psum, 32);
        lrun = lrun * alpha + psum;
        mrun = mn;

        #pragma unroll
        for (int kb = 0; kb < 4; ++kb) {
            __hip_bfloat16 t[4];
            #pragma unroll
            for (int r = 0; r < 4; ++r) t[r] = __float2bfloat16(p[kb * 4 + r]);
            *(uint2*)(Psw + l * 144 + kb * 32 + quad * 8) = *(const uint2*)t;
        }

        float a0 = __shfl(alpha, quad * 4 + 0);
        float a1 = __shfl(alpha, quad * 4 + 1);
        float a2 = __shfl(alpha, quad * 4 + 2);
        float a3 = __shfl(alpha, quad * 4 + 3);
        #pragma unroll
        for (int db = 0; db < 4; ++db) {
            facc[db][0] *= a0; facc[db][1] *= a1;
            facc[db][2] *= a2; facc[db][3] *= a3;
        }

        short8 pf0 = *(const short8*)(Psw + l * 144 + quad * 16);
        short8 pf1 = *(const short8*)(Psw + l * 144 + 64 + quad * 16);
        #pragma unroll
        for (int db = 0; db < 4; ++db) {
            int d = db * 16 + l;
            int o3 = (d >> 3) & 7;
            short8 v0 = *(const short8*)(Vt[buf] + d * 144 + ((quad ^ o3) << 4));
            short8 v1 = *(const short8*)(Vt[buf] + d * 144 + (((4 + quad) ^ o3) << 4));
            facc[db] = __builtin_amdgcn_mfma_f32_16x16x32_bf16(pf0, v0, facc[db], 0, 0, 0);
            facc[db] = __builtin_amdgcn_mfma_f32_16x16x32_bf16(pf1, v1, facc[db], 0, 0, 0);
        }
    };

    GKV(0, kA0, kA1, vA0, vA1);
    #pragma unroll 1
    for (int kt = 0; kt < 16; kt += 2) {
        WKV(0, kA0, kA1, vA0, vA1);
        __syncthreads();
        GKV(kt + 1, kB0, kB1, vB0, vB1);
        compute(0);
        WKV(1, kB0, kB1, vB0, vB1);
        __syncthreads();
        if (kt + 2 < 16) GKV(kt + 2, kA0, kA1, vA0, vA1);
        compute(1);
    }
#undef GKV
#undef WKV

    float il0 = 1.f / __shfl(lrun, quad * 4 + 0);
    float il1 = 1.f / __shfl(lrun, quad * 4 + 1);
    float il2 = 1.f / __shfl(lrun, quad * 4 + 2);
    float il3 = 1.f / __shfl(lrun, quad * 4 + 3);
    __hip_bfloat16* orow =
        o_out + (long)(b * 1024 + qt * 64 + wave * 16) * CDIM + hh * DHEAD;
    #pragma unroll
    for (int db = 0; db < 4; ++db) {
        int col = db * 16 + l;
        orow[(quad * 4 + 0) * CDIM + col] = __float2bfloat16(facc[db][0] * il0);
        orow[(quad * 4 + 1) * CDIM + col] = __float2bfloat16(facc[db][1] * il1);
        orow[(quad * 4 + 2) * CDIM + col] = __float2bfloat16(facc[db][2] * il2);
        orow[(quad * 4 + 3) * CDIM + col] = __float2bfloat16(facc[db][3] * il3);
    }
}

// ---------------------------------------------------------------------------
extern "C" void kernel_launch(void* const* d_in, const int* in_sizes, int n_in,
                              void* d_out, int out_size, void* d_ws, size_t ws_size,
                              hipStream_t stream)
{
    const float* x      = (const float*)d_in[0];
    const float* qkv_w  = (const float*)d_in[1];
    const float* proj_w = (const float*)d_in[2];
    const float* proj_b = (const float*)d_in[3];
    const float* fc1_w  = (const float*)d_in[4];
    const float* fc1_b  = (const float*)d_in[5];
    const float* fc2_w  = (const float*)d_in[6];
    const float* fc2_b  = (const float*)d_in[7];
    const float* ln1_g  = (const float*)d_in[8];
    const float* ln1_b  = (const float*)d_in[9];
    const float* ln2_g  = (const float*)d_in[10];
    const float* ln2_b  = (const float*)d_in[11];
    const float* lnh_g  = (const float*)d_in[12];
    const float* lnh_b  = (const float*)d_in[13];

    float* out = (float*)d_out;

    __hip_bfloat16* wsb     = (__hip_bfloat16*)d_ws;
    __hip_bfloat16* qkvw_bf = wsb;
    __hip_bfloat16* fc1w_bf = qkvw_bf + 3l * 1024 * 1024;
    __hip_bfloat16* fc2w_bf = fc1w_bf + 4l * 1024 * 1024;
    __hip_bfloat16* projw_bf= fc2w_bf + 4l * 1024 * 1024;
    __hip_bfloat16* h_bf    = projw_bf + 1l * 1024 * 1024;
    __hip_bfloat16* qkv_bf  = h_bf + 4l * 1024 * 1024;
    __hip_bfloat16* o_bf    = qkv_bf + 12l * 1024 * 1024;
    __hip_bfloat16* u_bf    = o_bf + 4l * 1024 * 1024;

    // 0. all weights fp32 -> bf16
    cvt_all<<<12288, 256, 0, stream>>>(qkv_w, fc1_w, fc2_w, proj_w, qkvw_bf);

    // 1. h = LN1(x)
    ln_f32_kernel<<<TOKENS, 256, 0, stream>>>(x, ln1_g, ln1_b, h_bf, CDIM);
    // 2. qkv = h @ qkv_w^T  (768 blocks, 3/CU)
    gemm32q<<<dim3(3072 / 128, TOKENS / 128), 256, 0, stream>>>(
        h_bf, qkvw_bf, nullptr, qkv_bf, TOKENS, 3072, CDIM, 0);
    // 3. o = attention(qkv)
    attn_mfma<<<1024, 256, 0, stream>>>(qkv_bf, o_bf);
    // 4. out = x + o @ proj_w^T + proj_b  (1024 blocks, 4/CU)
    gemm64g<<<dim3(CDIM / 64, TOKENS / 64), 256, 0, stream>>>(
        o_bf, projw_bf, proj_b, x, out, TOKENS, CDIM, CDIM);
    // 5. h2 = LN2(out)
    ln_f32_kernel<<<TOKENS, 256, 0, stream>>>(out, ln2_g, ln2_b, h_bf, CDIM);
    // 6. u = gelu(h2 @ fc1_w^T + fc1_b)  (1024 blocks, 4/CU)
    gemm32q<<<dim3(HID / 128, TOKENS / 128), 256, 0, stream>>>(
        h_bf, fc1w_bf, fc1_b, u_bf, TOKENS, HID, CDIM, 1);
    // 7. u = LNh(u) in place
    ln_bf16_kernel<<<TOKENS, 256, 0, stream>>>(u_bf, lnh_g, lnh_b, u_bf, HID);
    // 8. out = out + u @ fc2_w^T + fc2_b  (1024 blocks, 4/CU)
    gemm64g<<<dim3(CDIM / 64, TOKENS / 64), 256, 0, stream>>>(
        u_bf, fc2w_bf, fc2_b, out, out, TOKENS, CDIM, HID);
}